// Round 1
// baseline (3403.801 us; speedup 1.0000x reference)
//
#include <hip/hip_runtime.h>
#include <math.h>

#define NN 25000
#define NE 400000

__device__ __forceinline__ float lrelu(float x){ return x > 0.f ? x : 0.01f*x; }
__device__ __forceinline__ float elu1(float x){ return x > 0.f ? x : (__expf(x)-1.f); }
__device__ __forceinline__ float sigm(float x){ return 1.f/(1.f+__expf(-x)); }
__device__ __forceinline__ float tanh_fast(float x){ float e=__expf(2.f*x); return 1.f - 2.f/(e+1.f); }
// monotone float<->uint encoding for atomicMax on floats
__device__ __forceinline__ unsigned fenc(float f){ unsigned u=__float_as_uint(f); return (u&0x80000000u)? ~u : (u|0x80000000u); }
__device__ __forceinline__ float fdec(unsigned k){ return __uint_as_float((k&0x80000000u)? (k^0x80000000u) : ~k); }

// ---------------- layer 0 node precompute ----------------
// A[n]  = lrelu(x[n] @ atom_fc_w^T + ba)              [N][128]
// B[n]  = x[n] @ neighbor_fc_w[:, :39]^T + bn         [N][128]  (edge part + lrelu later)
// T[n]  = A[n] @ attend_w^T + tb                      [N][128]
// GH[n] = A[n] @ w_hh^T + b_hh                        [N][384]
// di[n] = dot(A[n], align_w[0:128])
__global__ __launch_bounds__(256) void k_l0_node(
    const float* __restrict__ x,
    const float* __restrict__ wa, const float* __restrict__ ba,
    const float* __restrict__ wn, const float* __restrict__ bn,
    const float* __restrict__ aw,
    const float* __restrict__ tw, const float* __restrict__ tb,
    const float* __restrict__ whh, const float* __restrict__ bhh,
    float* __restrict__ A, float* __restrict__ B, float* __restrict__ T,
    float* __restrict__ GH, float* __restrict__ di)
{
    __shared__ float xs[32][40];
    __shared__ float As[32][130];
    const int t = threadIdx.x;
    const int base = blockIdx.x * 32;
    for (int idx = t; idx < 32*39; idx += 256){
        int nn = idx / 39, k = idx - nn*39;
        int node = base + nn;
        xs[nn][k] = (node < NN) ? x[(size_t)node*39 + k] : 0.f;
    }
    __syncthreads();
    const int j = t & 127;
    const int g = t >> 7;  // nodes g*16 .. g*16+15
    {
        float accA[16], accB[16];
        #pragma unroll
        for (int nn=0; nn<16; ++nn){ accA[nn]=0.f; accB[nn]=0.f; }
        for (int k=0; k<39; ++k){
            float wva = wa[j*39+k];
            float wvb = wn[j*49+k];
            #pragma unroll
            for (int nn=0; nn<16; ++nn){
                float xv = xs[g*16+nn][k];
                accA[nn] += xv*wva;
                accB[nn] += xv*wvb;
            }
        }
        float bav = ba[j], bnv = bn[j];
        #pragma unroll
        for (int nn=0; nn<16; ++nn){
            int node = base + g*16 + nn;
            float av = lrelu(accA[nn] + bav);
            As[g*16+nn][j] = av;
            if (node < NN){
                A[(size_t)node*128 + j] = av;
                B[(size_t)node*128 + j] = accB[nn] + bnv;
            }
        }
    }
    __syncthreads();
    if (t < 32){
        int node = base + t;
        if (node < NN){
            float d = 0.f;
            for (int k=0; k<128; ++k) d += As[t][k]*aw[k];
            di[node] = d;
        }
    }
    {   // T
        float acc[16];
        #pragma unroll
        for (int nn=0; nn<16; ++nn) acc[nn]=0.f;
        for (int k=0; k<128; ++k){
            float wv = tw[j*128+k];
            #pragma unroll
            for (int nn=0; nn<16; ++nn) acc[nn] += As[g*16+nn][k]*wv;
        }
        float tbv = tb[j];
        #pragma unroll
        for (int nn=0; nn<16; ++nn){
            int node = base + g*16 + nn;
            if (node < NN) T[(size_t)node*128 + j] = acc[nn] + tbv;
        }
    }
    for (int cb=0; cb<3; ++cb){   // GH
        int jc = cb*128 + j;
        float acc[16];
        #pragma unroll
        for (int nn=0; nn<16; ++nn) acc[nn]=0.f;
        for (int k=0; k<128; ++k){
            float wv = whh[jc*128+k];
            #pragma unroll
            for (int nn=0; nn<16; ++nn) acc[nn] += As[g*16+nn][k]*wv;
        }
        float bv = bhh[jc];
        #pragma unroll
        for (int nn=0; nn<16; ++nn){
            int node = base + g*16 + nn;
            if (node < NN) GH[(size_t)node*384 + jc] = acc[nn] + bv;
        }
    }
}

// ---------------- layer 0 align (per edge) ----------------
// xj = lrelu(B[src] + edge_attr @ Wn2^T); evu = lrelu(di[dst] + dot(xj, aw[128:256]) + ab)
#define EPW 8
__global__ __launch_bounds__(256) void k_l0_align(
    const int* __restrict__ srcA, const int* __restrict__ dstA,
    const float* __restrict__ ea,
    const float* __restrict__ B,
    const float* __restrict__ wn,
    const float* __restrict__ aw, const float* __restrict__ ab,
    const float* __restrict__ di,
    float* __restrict__ evu, unsigned* __restrict__ m)
{
    const int t = threadIdx.x;
    const int lane = t & 63;
    const int w = t >> 6;
    float wn2a[10], wn2b[10];
    #pragma unroll
    for (int k=0; k<10; ++k){
        wn2a[k] = wn[lane*49 + 39 + k];
        wn2b[k] = wn[(lane+64)*49 + 39 + k];
    }
    const float awa = aw[128+lane], awb = aw[128+64+lane];
    const float abv = ab[0];
    const int e0 = (blockIdx.x*4 + w) * EPW;
    for (int i=0; i<EPW; ++i){
        int e = e0 + i;
        int s = srcA[e];
        int d = dstA[e];
        float v1 = B[(size_t)s*128 + lane];
        float v2 = B[(size_t)s*128 + 64 + lane];
        #pragma unroll
        for (int k=0; k<10; ++k){
            float ev = ea[(size_t)e*10 + k];
            v1 += ev*wn2a[k];
            v2 += ev*wn2b[k];
        }
        v1 = lrelu(v1); v2 = lrelu(v2);
        float p = v1*awa + v2*awb;
        #pragma unroll
        for (int off=32; off; off>>=1) p += __shfl_xor(p, off);
        if (lane == 0){
            float ev = lrelu(p + di[d] + abv);
            evu[e] = ev;
            atomicMax(m + s, fenc(ev));
        }
    }
}

// ---------------- layer 1 align (per edge, trivial) ----------------
__global__ __launch_bounds__(256) void k_l1_align(
    const int* __restrict__ srcA, const int* __restrict__ dstA,
    const float* __restrict__ di, const float* __restrict__ dj,
    const float* __restrict__ ab,
    float* __restrict__ evu, unsigned* __restrict__ m)
{
    int e = blockIdx.x*256 + threadIdx.x;
    if (e < NE){
        int s = srcA[e], d = dstA[e];
        float v = lrelu(di[d] + dj[s] + ab[0]);
        evu[e] = v;
        atomicMax(m + s, fenc(v));
    }
}

// ---------------- softmax normalize: ex = exp(evu - m[src]); s[src] += ex ----------------
__global__ __launch_bounds__(256) void k_norm(
    const int* __restrict__ srcA, const unsigned* __restrict__ m,
    float* __restrict__ ex, float* __restrict__ s)
{
    int e = blockIdx.x*256 + threadIdx.x;
    if (e < NE){
        int sn = srcA[e];
        float v = __expf(ex[e] - fdec(m[sn]));
        ex[e] = v;
        atomicAdd(s + sn, v);
    }
}

// ---------------- heavy per-edge: c = elu(avu*T[dst]); gi = c@wih^T; GRU; out[dst] += h ----------------
__global__ __launch_bounds__(256) void k_edge_gru(
    const int* __restrict__ srcA, const int* __restrict__ dstA,
    const float* __restrict__ exA, const float* __restrict__ sA,
    const float* __restrict__ T, const float* __restrict__ GH,
    const float* __restrict__ Hp, const float* __restrict__ wih,
    const float* __restrict__ bih, float* __restrict__ out)
{
    __shared__ __align__(16) float c_lds[64*132];
    __shared__ int dsts[64];
    __shared__ float av[64];
    const int t = threadIdx.x;
    const int e0 = blockIdx.x << 6;
    if (t < 64){
        int e = e0 + t;
        int s = srcA[e];
        dsts[t] = dstA[e];
        av[t] = exA[e] / (sA[s] + 1e-16f);
    }
    __syncthreads();
    {
        const int j = t & 127, g = t >> 7;
        #pragma unroll 4
        for (int nn=0; nn<32; ++nn){
            int el = (g<<5) + nn;
            float tv = T[(size_t)dsts[el]*128 + j];
            c_lds[el*132 + j] = elu1(av[el]*tv);
        }
    }
    __syncthreads();
    const int e2 = t & 31;
    const int cg = t >> 5;     // 0..7, 16 base cols each
    float hreg[2][8][2];
    #pragma unroll
    for (int jh=0; jh<2; ++jh){
        float acc[8][3][2];
        #pragma unroll
        for (int a=0; a<8; ++a)
            #pragma unroll
            for (int b=0; b<3; ++b){ acc[a][b][0]=0.f; acc[a][b][1]=0.f; }
        for (int k=0; k<128; k+=4){
            const float4 c0 = *(const float4*)&c_lds[e2*132 + k];
            const float4 c1 = *(const float4*)&c_lds[(e2+32)*132 + k];
            #pragma unroll
            for (int jj=0; jj<8; ++jj){
                const int j = (cg<<4) + (jh<<3) + jj;
                const float4 wr = *(const float4*)&wih[(size_t)(j      )*128 + k];
                const float4 wz = *(const float4*)&wih[(size_t)(j + 128)*128 + k];
                const float4 wq = *(const float4*)&wih[(size_t)(j + 256)*128 + k];
                acc[jj][0][0] += c0.x*wr.x + c0.y*wr.y + c0.z*wr.z + c0.w*wr.w;
                acc[jj][1][0] += c0.x*wz.x + c0.y*wz.y + c0.z*wz.z + c0.w*wz.w;
                acc[jj][2][0] += c0.x*wq.x + c0.y*wq.y + c0.z*wq.z + c0.w*wq.w;
                acc[jj][0][1] += c1.x*wr.x + c1.y*wr.y + c1.z*wr.z + c1.w*wr.w;
                acc[jj][1][1] += c1.x*wz.x + c1.y*wz.y + c1.z*wz.z + c1.w*wz.w;
                acc[jj][2][1] += c1.x*wq.x + c1.y*wq.y + c1.z*wq.z + c1.w*wq.w;
            }
        }
        #pragma unroll
        for (int jj=0; jj<8; ++jj){
            const int j = (cg<<4) + (jh<<3) + jj;
            const float br = bih[j], bz = bih[128+j], bq = bih[256+j];
            #pragma unroll
            for (int ee=0; ee<2; ++ee){
                const int el = e2 + (ee<<5);
                const int d = dsts[el];
                const float* gh = GH + (size_t)d*384;
                float r = sigm(acc[jj][0][ee] + br + gh[j]);
                float z = sigm(acc[jj][1][ee] + bz + gh[128+j]);
                float n = tanh_fast(acc[jj][2][ee] + bq + r*gh[256+j]);
                float hp = Hp[(size_t)d*128 + j];
                hreg[jh][jj][ee] = (1.f - z)*n + z*hp;
            }
        }
    }
    __syncthreads();   // all c_lds reads done
    #pragma unroll
    for (int jh=0; jh<2; ++jh)
        #pragma unroll
        for (int jj=0; jj<8; ++jj){
            const int j = (cg<<4) + (jh<<3) + jj;
            c_lds[e2*132 + j]      = hreg[jh][jj][0];
            c_lds[(e2+32)*132 + j] = hreg[jh][jj][1];
        }
    __syncthreads();
    {
        const int j = t & 127, g = t >> 7;
        #pragma unroll 4
        for (int nn=0; nn<32; ++nn){
            int el = (g<<5) + nn;
            atomicAdd(out + (size_t)dsts[el]*128 + j, c_lds[el*132 + j]);
        }
    }
}

// ---------------- layer 1 node precompute ----------------
__global__ __launch_bounds__(256) void k_l1_node(
    const float* __restrict__ x1,
    const float* __restrict__ aw,
    const float* __restrict__ tw, const float* __restrict__ tb,
    const float* __restrict__ whh, const float* __restrict__ bhh,
    float* __restrict__ T, float* __restrict__ GH,
    float* __restrict__ di, float* __restrict__ dj)
{
    __shared__ float xs[32*132];
    const int t = threadIdx.x;
    const int base = blockIdx.x * 32;
    const int j = t & 127, g = t >> 7;
    #pragma unroll
    for (int nn=0; nn<16; ++nn){
        int row = g*16 + nn;
        int node = base + row;
        xs[row*132 + j] = (node < NN) ? x1[(size_t)node*128 + j] : 0.f;
    }
    __syncthreads();
    if (t < 64){
        int row = t & 31, which = t >> 5;
        int node = base + row;
        if (node < NN){
            const float* a = aw + which*128;
            float dsum = 0.f;
            for (int k=0; k<128; ++k) dsum += xs[row*132 + k]*a[k];
            (which ? dj : di)[node] = dsum;
        }
    }
    {
        float acc[16];
        #pragma unroll
        for (int nn=0; nn<16; ++nn) acc[nn]=0.f;
        for (int k=0; k<128; ++k){
            float wv = tw[j*128+k];
            #pragma unroll
            for (int nn=0; nn<16; ++nn) acc[nn] += xs[(g*16+nn)*132 + k]*wv;
        }
        float tbv = tb[j];
        #pragma unroll
        for (int nn=0; nn<16; ++nn){
            int node = base + g*16 + nn;
            if (node < NN) T[(size_t)node*128 + j] = acc[nn] + tbv;
        }
    }
    for (int cb=0; cb<3; ++cb){
        int jc = cb*128 + j;
        float acc[16];
        #pragma unroll
        for (int nn=0; nn<16; ++nn) acc[nn]=0.f;
        for (int k=0; k<128; ++k){
            float wv = whh[jc*128+k];
            #pragma unroll
            for (int nn=0; nn<16; ++nn) acc[nn] += xs[(g*16+nn)*132 + k]*wv;
        }
        float bv = bhh[jc];
        #pragma unroll
        for (int nn=0; nn<16; ++nn){
            int node = base + g*16 + nn;
            if (node < NN) GH[(size_t)node*384 + jc] = acc[nn] + bv;
        }
    }
}

extern "C" void kernel_launch(void* const* d_in, const int* in_sizes, int n_in,
                              void* d_out, int out_size, void* d_ws, size_t ws_size,
                              hipStream_t stream) {
    const float* x    = (const float*)d_in[0];
    const int*   eidx = (const int*)d_in[1];
    const int*   esrc = eidx;
    const int*   edst = eidx + NE;
    const float* ea   = (const float*)d_in[2];
    const float* a_w  = (const float*)d_in[3];
    const float* a_b  = (const float*)d_in[4];
    const float* n_w  = (const float*)d_in[5];
    const float* n_b  = (const float*)d_in[6];
    const float* al_w0= (const float*)d_in[7];
    const float* al_b0= (const float*)d_in[8];
    const float* t_w0 = (const float*)d_in[9];
    const float* t_b0 = (const float*)d_in[10];
    const float* wih0 = (const float*)d_in[11];
    const float* whh0 = (const float*)d_in[12];
    const float* bih0 = (const float*)d_in[13];
    const float* bhh0 = (const float*)d_in[14];
    const float* al_w1= (const float*)d_in[15];
    const float* al_b1= (const float*)d_in[16];
    const float* t_w1 = (const float*)d_in[17];
    const float* t_b1 = (const float*)d_in[18];
    const float* wih1 = (const float*)d_in[19];
    const float* whh1 = (const float*)d_in[20];
    const float* bih1 = (const float*)d_in[21];
    const float* bhh1 = (const float*)d_in[22];

    float* ws   = (float*)d_ws;
    float* A    = ws;
    float* B    = A   + (size_t)NN*128;
    float* T    = B   + (size_t)NN*128;
    float* GH   = T   + (size_t)NN*128;
    float* evu  = GH  + (size_t)NN*384;
    float* di   = evu + NE;
    float* dj   = di  + NN;
    float* out0 = dj  + NN;
    unsigned* m0 = (unsigned*)(out0 + (size_t)NN*128);
    float*    s0 = (float*)(m0 + NN);
    unsigned* m1 = (unsigned*)(s0 + NN);
    float*    s1 = (float*)(m1 + NN);

    // zero accumulators: out0, m0, s0, m1, s1 are contiguous
    hipMemsetAsync(out0, 0, ((size_t)NN*128 + 4*(size_t)NN)*sizeof(float), stream);
    hipMemsetAsync(d_out, 0, (size_t)NN*128*sizeof(float), stream);

    dim3 blk(256);
    // ---- layer 0 ----
    k_l0_node<<<dim3((NN+31)/32), blk, 0, stream>>>(x, a_w, a_b, n_w, n_b, al_w0,
                                                    t_w0, t_b0, whh0, bhh0,
                                                    A, B, T, GH, di);
    k_l0_align<<<dim3(NE/(4*EPW)), blk, 0, stream>>>(esrc, edst, ea, B, n_w, al_w0, al_b0, di, evu, m0);
    k_norm<<<dim3((NE+255)/256), blk, 0, stream>>>(esrc, m0, evu, s0);
    k_edge_gru<<<dim3(NE/64), blk, 0, stream>>>(esrc, edst, evu, s0, T, GH, A, wih0, bih0, out0);
    // ---- layer 1 ----
    k_l1_node<<<dim3((NN+31)/32), blk, 0, stream>>>(out0, al_w1, t_w1, t_b1, whh1, bhh1, T, GH, di, dj);
    k_l1_align<<<dim3((NE+255)/256), blk, 0, stream>>>(esrc, edst, di, dj, al_b1, evu, m1);
    k_norm<<<dim3((NE+255)/256), blk, 0, stream>>>(esrc, m1, evu, s1);
    k_edge_gru<<<dim3(NE/64), blk, 0, stream>>>(esrc, edst, evu, s1, T, GH, out0, wih1, bih1, (float*)d_out);
}

// Round 2
// 1027.679 us; speedup vs baseline: 3.3121x; 3.3121x over previous
//
#include <hip/hip_runtime.h>
#include <hip/hip_bf16.h>
#include <math.h>

#define NN 25000
#define NE 400000

typedef __attribute__((ext_vector_type(8))) short bf16x8;
typedef __attribute__((ext_vector_type(4))) float f32x4;

__device__ __forceinline__ float lrelu(float x){ return x > 0.f ? x : 0.01f*x; }
__device__ __forceinline__ float elu1(float x){ return x > 0.f ? x : (__expf(x)-1.f); }
__device__ __forceinline__ float sigm(float x){ return 1.f/(1.f+__expf(-x)); }
__device__ __forceinline__ float tanh_fast(float x){ float e=__expf(2.f*x); return 1.f - 2.f/(e+1.f); }
__device__ __forceinline__ unsigned fenc(float f){ unsigned u=__float_as_uint(f); return (u&0x80000000u)? ~u : (u|0x80000000u); }
__device__ __forceinline__ float fdec(unsigned k){ return __uint_as_float((k&0x80000000u)? (k^0x80000000u) : ~k); }
__device__ __forceinline__ short f2bf(float f){
    union { float f; unsigned u; } v; v.f = f;
    unsigned r = v.u + 0x7fff + ((v.u >> 16) & 1);   // RNE
    return (short)(r >> 16);
}

// ---------------- pack w_ih into MFMA B-fragment order, bf16 ----------------
// out[((tile*4+ks)*64+lane)*8+i] = wih[(tile*16+(lane&15))*128 + ks*32 + (lane>>4)*8 + i]
__global__ __launch_bounds__(256) void k_pack_wih(const float* __restrict__ wih,
                                                  short* __restrict__ out)
{
    int idx = blockIdx.x*256 + threadIdx.x;     // 24*4*64*8 = 49152
    if (idx < 49152){
        int i    = idx & 7;
        int lane = (idx >> 3) & 63;
        int ks   = (idx >> 9) & 3;
        int tile = idx >> 11;
        int row  = tile*16 + (lane & 15);
        int k    = ks*32 + ((lane >> 4) << 3) + i;
        out[idx] = f2bf(wih[row*128 + k]);
    }
}

// ---------------- layer 0 node precompute ----------------
__global__ __launch_bounds__(256) void k_l0_node(
    const float* __restrict__ x,
    const float* __restrict__ wa, const float* __restrict__ ba,
    const float* __restrict__ wn, const float* __restrict__ bn,
    const float* __restrict__ aw,
    const float* __restrict__ tw, const float* __restrict__ tb,
    const float* __restrict__ whh, const float* __restrict__ bhh,
    float* __restrict__ A, float* __restrict__ B, float* __restrict__ T,
    float* __restrict__ GH, float* __restrict__ di)
{
    __shared__ float xs[32][40];
    __shared__ float As[32][130];
    const int t = threadIdx.x;
    const int base = blockIdx.x * 32;
    for (int idx = t; idx < 32*39; idx += 256){
        int nn = idx / 39, k = idx - nn*39;
        int node = base + nn;
        xs[nn][k] = (node < NN) ? x[(size_t)node*39 + k] : 0.f;
    }
    __syncthreads();
    const int j = t & 127;
    const int g = t >> 7;
    {
        float accA[16], accB[16];
        #pragma unroll
        for (int nn=0; nn<16; ++nn){ accA[nn]=0.f; accB[nn]=0.f; }
        for (int k=0; k<39; ++k){
            float wva = wa[j*39+k];
            float wvb = wn[j*49+k];
            #pragma unroll
            for (int nn=0; nn<16; ++nn){
                float xv = xs[g*16+nn][k];
                accA[nn] += xv*wva;
                accB[nn] += xv*wvb;
            }
        }
        float bav = ba[j], bnv = bn[j];
        #pragma unroll
        for (int nn=0; nn<16; ++nn){
            int node = base + g*16 + nn;
            float av = lrelu(accA[nn] + bav);
            As[g*16+nn][j] = av;
            if (node < NN){
                A[(size_t)node*128 + j] = av;
                B[(size_t)node*128 + j] = accB[nn] + bnv;
            }
        }
    }
    __syncthreads();
    if (t < 32){
        int node = base + t;
        if (node < NN){
            float d = 0.f;
            for (int k=0; k<128; ++k) d += As[t][k]*aw[k];
            di[node] = d;
        }
    }
    {
        float acc[16];
        #pragma unroll
        for (int nn=0; nn<16; ++nn) acc[nn]=0.f;
        for (int k=0; k<128; ++k){
            float wv = tw[j*128+k];
            #pragma unroll
            for (int nn=0; nn<16; ++nn) acc[nn] += As[g*16+nn][k]*wv;
        }
        float tbv = tb[j];
        #pragma unroll
        for (int nn=0; nn<16; ++nn){
            int node = base + g*16 + nn;
            if (node < NN) T[(size_t)node*128 + j] = acc[nn] + tbv;
        }
    }
    for (int cb=0; cb<3; ++cb){
        int jc = cb*128 + j;
        float acc[16];
        #pragma unroll
        for (int nn=0; nn<16; ++nn) acc[nn]=0.f;
        for (int k=0; k<128; ++k){
            float wv = whh[jc*128+k];
            #pragma unroll
            for (int nn=0; nn<16; ++nn) acc[nn] += As[g*16+nn][k]*wv;
        }
        float bv = bhh[jc];
        #pragma unroll
        for (int nn=0; nn<16; ++nn){
            int node = base + g*16 + nn;
            if (node < NN) GH[(size_t)node*384 + jc] = acc[nn] + bv;
        }
    }
}

// ---------------- layer 0 align (per edge) ----------------
#define EPW 8
__global__ __launch_bounds__(256) void k_l0_align(
    const int* __restrict__ srcA, const int* __restrict__ dstA,
    const float* __restrict__ ea,
    const float* __restrict__ B,
    const float* __restrict__ wn,
    const float* __restrict__ aw, const float* __restrict__ ab,
    const float* __restrict__ di,
    float* __restrict__ evu, unsigned* __restrict__ m)
{
    const int t = threadIdx.x;
    const int lane = t & 63;
    const int w = t >> 6;
    float wn2a[10], wn2b[10];
    #pragma unroll
    for (int k=0; k<10; ++k){
        wn2a[k] = wn[lane*49 + 39 + k];
        wn2b[k] = wn[(lane+64)*49 + 39 + k];
    }
    const float awa = aw[128+lane], awb = aw[128+64+lane];
    const float abv = ab[0];
    const int e0 = (blockIdx.x*4 + w) * EPW;
    for (int i=0; i<EPW; ++i){
        int e = e0 + i;
        int s = srcA[e];
        int d = dstA[e];
        float v1 = B[(size_t)s*128 + lane];
        float v2 = B[(size_t)s*128 + 64 + lane];
        #pragma unroll
        for (int k=0; k<10; ++k){
            float ev = ea[(size_t)e*10 + k];
            v1 += ev*wn2a[k];
            v2 += ev*wn2b[k];
        }
        v1 = lrelu(v1); v2 = lrelu(v2);
        float p = v1*awa + v2*awb;
        #pragma unroll
        for (int off=32; off; off>>=1) p += __shfl_xor(p, off);
        if (lane == 0){
            float ev = lrelu(p + di[d] + abv);
            evu[e] = ev;
            atomicMax(m + s, fenc(ev));
        }
    }
}

// ---------------- layer 1 align ----------------
__global__ __launch_bounds__(256) void k_l1_align(
    const int* __restrict__ srcA, const int* __restrict__ dstA,
    const float* __restrict__ di, const float* __restrict__ dj,
    const float* __restrict__ ab,
    float* __restrict__ evu, unsigned* __restrict__ m)
{
    int e = blockIdx.x*256 + threadIdx.x;
    if (e < NE){
        int s = srcA[e], d = dstA[e];
        float v = lrelu(di[d] + dj[s] + ab[0]);
        evu[e] = v;
        atomicMax(m + s, fenc(v));
    }
}

// ---------------- softmax normalize ----------------
__global__ __launch_bounds__(256) void k_norm(
    const int* __restrict__ srcA, const unsigned* __restrict__ m,
    float* __restrict__ ex, float* __restrict__ s)
{
    int e = blockIdx.x*256 + threadIdx.x;
    if (e < NE){
        int sn = srcA[e];
        float v = __expf(ex[e] - fdec(m[sn]));
        ex[e] = v;
        atomicAdd(s + sn, v);
    }
}

// ---------------- heavy per-edge: MFMA edition ----------------
// 64 edges/block, 512 threads (8 waves). c[64][128]bf16 in LDS (272B pitch).
// gi = c @ wih^T via mfma_f32_16x16x32_bf16; wave w owns cols w*16..w*16+15 of all
// 3 gates (b-frags pre-packed). Epilogue GRU in C-frag layout; h staged in LDS
// (reusing c space) for coalesced 512B atomics.
__global__ __launch_bounds__(512) void k_edge_gru(
    const int* __restrict__ srcA, const int* __restrict__ dstA,
    const float* __restrict__ exA, const float* __restrict__ sA,
    const float* __restrict__ T, const float* __restrict__ GH,
    const float* __restrict__ Hp, const short* __restrict__ wpack,
    const float* __restrict__ bih, float* __restrict__ out)
{
    __shared__ __align__(16) char smem[64*132*4];   // c: 64*272=17408B ; h: 64*132*4=33792B
    __shared__ int dsts[64];
    __shared__ float av[64];
    const int t = threadIdx.x;
    const int e0 = blockIdx.x << 6;
    if (t < 64){
        int e = e0 + t;
        int s = srcA[e];
        dsts[t] = dstA[e];
        av[t] = exA[e] / (sA[s] + 1e-16f);
    }
    __syncthreads();
    // ---- phase 2: c = elu(avu * T[dst]) -> bf16 LDS ----
    {
        const int q = t & 31;          // col quad
        const int eo = t >> 5;         // 0..15
        #pragma unroll
        for (int it=0; it<4; ++it){
            int e = it*16 + eo;
            int d = dsts[e];
            float a = av[e];
            float4 tv = *(const float4*)&T[(size_t)d*128 + q*4];
            union { short s[4]; int2 v; } u;
            u.s[0] = f2bf(elu1(a*tv.x));
            u.s[1] = f2bf(elu1(a*tv.y));
            u.s[2] = f2bf(elu1(a*tv.z));
            u.s[3] = f2bf(elu1(a*tv.w));
            *(int2*)(smem + e*272 + q*8) = u.v;
        }
    }
    __syncthreads();
    // ---- phase 3: MFMA ----
    const int w = t >> 6;          // wave 0..7
    const int lane = t & 63;
    const int l15 = lane & 15;
    const int lhi = lane >> 4;     // 0..3
    f32x4 acc[4][3];
    #pragma unroll
    for (int g=0; g<3; ++g){
        float bv = bih[g*128 + w*16 + l15];
        #pragma unroll
        for (int m=0; m<4; ++m) acc[m][g] = (f32x4){bv, bv, bv, bv};
    }
    #pragma unroll
    for (int ks=0; ks<4; ++ks){
        bf16x8 bf[3];
        #pragma unroll
        for (int g=0; g<3; ++g){
            int nt = g*8 + w;
            bf[g] = *(const bf16x8*)(wpack + (size_t)((nt*4 + ks)*64 + lane)*8);
        }
        bf16x8 af[4];
        #pragma unroll
        for (int m=0; m<4; ++m){
            int row = m*16 + l15;
            af[m] = *(const bf16x8*)(smem + row*272 + ks*64 + (lhi<<4));
        }
        #pragma unroll
        for (int m=0; m<4; ++m)
            #pragma unroll
            for (int g=0; g<3; ++g)
                acc[m][g] = __builtin_amdgcn_mfma_f32_16x16x32_bf16(af[m], bf[g], acc[m][g], 0, 0, 0);
    }
    __syncthreads();   // all c reads done; smem becomes h
    // ---- phase 4: GRU epilogue in C-frag layout ----
    {
        const int jb = w*16 + l15;                 // 0..127
        float* hlds = (float*)smem;
        #pragma unroll
        for (int m=0; m<4; ++m){
            #pragma unroll
            for (int reg=0; reg<4; ++reg){
                int e = m*16 + lhi*4 + reg;
                int d = dsts[e];
                const float* gh = GH + (size_t)d*384;
                float r = sigm(acc[m][0][reg] + gh[jb]);
                float z = sigm(acc[m][1][reg] + gh[128+jb]);
                float n = tanh_fast(acc[m][2][reg] + r*gh[256+jb]);
                float hp = Hp[(size_t)d*128 + jb];
                hlds[e*132 + jb] = (1.f - z)*n + z*hp;
            }
        }
    }
    __syncthreads();
    // ---- phase 5: coalesced scatter-add ----
    {
        const int j = t & 127, eg = t >> 7;        // eg 0..3
        const float* hlds = (const float*)smem;
        #pragma unroll
        for (int el=0; el<16; ++el){
            int e = eg*16 + el;
            atomicAdd(out + (size_t)dsts[e]*128 + j, hlds[e*132 + j]);
        }
    }
}

// ---------------- layer 1 node precompute ----------------
__global__ __launch_bounds__(256) void k_l1_node(
    const float* __restrict__ x1,
    const float* __restrict__ aw,
    const float* __restrict__ tw, const float* __restrict__ tb,
    const float* __restrict__ whh, const float* __restrict__ bhh,
    float* __restrict__ T, float* __restrict__ GH,
    float* __restrict__ di, float* __restrict__ dj)
{
    __shared__ float xs[32*132];
    const int t = threadIdx.x;
    const int base = blockIdx.x * 32;
    const int j = t & 127, g = t >> 7;
    #pragma unroll
    for (int nn=0; nn<16; ++nn){
        int row = g*16 + nn;
        int node = base + row;
        xs[row*132 + j] = (node < NN) ? x1[(size_t)node*128 + j] : 0.f;
    }
    __syncthreads();
    if (t < 64){
        int row = t & 31, which = t >> 5;
        int node = base + row;
        if (node < NN){
            const float* a = aw + which*128;
            float dsum = 0.f;
            for (int k=0; k<128; ++k) dsum += xs[row*132 + k]*a[k];
            (which ? dj : di)[node] = dsum;
        }
    }
    {
        float acc[16];
        #pragma unroll
        for (int nn=0; nn<16; ++nn) acc[nn]=0.f;
        for (int k=0; k<128; ++k){
            float wv = tw[j*128+k];
            #pragma unroll
            for (int nn=0; nn<16; ++nn) acc[nn] += xs[(g*16+nn)*132 + k]*wv;
        }
        float tbv = tb[j];
        #pragma unroll
        for (int nn=0; nn<16; ++nn){
            int node = base + g*16 + nn;
            if (node < NN) T[(size_t)node*128 + j] = acc[nn] + tbv;
        }
    }
    for (int cb=0; cb<3; ++cb){
        int jc = cb*128 + j;
        float acc[16];
        #pragma unroll
        for (int nn=0; nn<16; ++nn) acc[nn]=0.f;
        for (int k=0; k<128; ++k){
            float wv = whh[jc*128+k];
            #pragma unroll
            for (int nn=0; nn<16; ++nn) acc[nn] += xs[(g*16+nn)*132 + k]*wv;
        }
        float bv = bhh[jc];
        #pragma unroll
        for (int nn=0; nn<16; ++nn){
            int node = base + g*16 + nn;
            if (node < NN) GH[(size_t)node*384 + jc] = acc[nn] + bv;
        }
    }
}

extern "C" void kernel_launch(void* const* d_in, const int* in_sizes, int n_in,
                              void* d_out, int out_size, void* d_ws, size_t ws_size,
                              hipStream_t stream) {
    const float* x    = (const float*)d_in[0];
    const int*   eidx = (const int*)d_in[1];
    const int*   esrc = eidx;
    const int*   edst = eidx + NE;
    const float* ea   = (const float*)d_in[2];
    const float* a_w  = (const float*)d_in[3];
    const float* a_b  = (const float*)d_in[4];
    const float* n_w  = (const float*)d_in[5];
    const float* n_b  = (const float*)d_in[6];
    const float* al_w0= (const float*)d_in[7];
    const float* al_b0= (const float*)d_in[8];
    const float* t_w0 = (const float*)d_in[9];
    const float* t_b0 = (const float*)d_in[10];
    const float* wih0 = (const float*)d_in[11];
    const float* whh0 = (const float*)d_in[12];
    const float* bih0 = (const float*)d_in[13];
    const float* bhh0 = (const float*)d_in[14];
    const float* al_w1= (const float*)d_in[15];
    const float* al_b1= (const float*)d_in[16];
    const float* t_w1 = (const float*)d_in[17];
    const float* t_b1 = (const float*)d_in[18];
    const float* wih1 = (const float*)d_in[19];
    const float* whh1 = (const float*)d_in[20];
    const float* bih1 = (const float*)d_in[21];
    const float* bhh1 = (const float*)d_in[22];

    float* ws   = (float*)d_ws;
    float* A    = ws;
    float* B    = A   + (size_t)NN*128;
    float* T    = B   + (size_t)NN*128;
    float* GH   = T   + (size_t)NN*128;
    float* evu  = GH  + (size_t)NN*384;
    float* di   = evu + NE;
    float* dj   = di  + NN;
    float* out0 = dj  + NN;
    unsigned* m0 = (unsigned*)(out0 + (size_t)NN*128);
    float*    s0 = (float*)(m0 + NN);
    unsigned* m1 = (unsigned*)(s0 + NN);
    float*    s1 = (float*)(m1 + NN);
    short*    wp0 = (short*)(s1 + NN);
    short*    wp1 = wp0 + 49152;

    hipMemsetAsync(out0, 0, ((size_t)NN*128 + 4*(size_t)NN)*sizeof(float), stream);
    hipMemsetAsync(d_out, 0, (size_t)NN*128*sizeof(float), stream);

    dim3 blk(256);
    k_pack_wih<<<dim3(192), blk, 0, stream>>>(wih0, wp0);
    k_pack_wih<<<dim3(192), blk, 0, stream>>>(wih1, wp1);
    // ---- layer 0 ----
    k_l0_node<<<dim3((NN+31)/32), blk, 0, stream>>>(x, a_w, a_b, n_w, n_b, al_w0,
                                                    t_w0, t_b0, whh0, bhh0,
                                                    A, B, T, GH, di);
    k_l0_align<<<dim3(NE/(4*EPW)), blk, 0, stream>>>(esrc, edst, ea, B, n_w, al_w0, al_b0, di, evu, m0);
    k_norm<<<dim3((NE+255)/256), blk, 0, stream>>>(esrc, m0, evu, s0);
    k_edge_gru<<<dim3(NE/64), dim3(512), 0, stream>>>(esrc, edst, evu, s0, T, GH, A, wp0, bih0, out0);
    // ---- layer 1 ----
    k_l1_node<<<dim3((NN+31)/32), blk, 0, stream>>>(out0, al_w1, t_w1, t_b1, whh1, bhh1, T, GH, di, dj);
    k_l1_align<<<dim3((NE+255)/256), blk, 0, stream>>>(esrc, edst, di, dj, al_b1, evu, m1);
    k_norm<<<dim3((NE+255)/256), blk, 0, stream>>>(esrc, m1, evu, s1);
    k_edge_gru<<<dim3(NE/64), dim3(512), 0, stream>>>(esrc, edst, evu, s1, T, GH, out0, wp1, bih1, (float*)d_out);
}

// Round 3
// 904.082 us; speedup vs baseline: 3.7649x; 1.1367x over previous
//
#include <hip/hip_runtime.h>
#include <hip/hip_bf16.h>
#include <math.h>

#define NN 25000
#define NE 400000

typedef __attribute__((ext_vector_type(8))) short bf16x8;
typedef __attribute__((ext_vector_type(4))) float f32x4;

__device__ __forceinline__ float lrelu(float x){ return x > 0.f ? x : 0.01f*x; }
__device__ __forceinline__ float elu1(float x){ return x > 0.f ? x : (__expf(x)-1.f); }
__device__ __forceinline__ float sigm(float x){ return 1.f/(1.f+__expf(-x)); }
__device__ __forceinline__ float tanh_fast(float x){ float e=__expf(2.f*x); return 1.f - 2.f/(e+1.f); }
__device__ __forceinline__ unsigned fenc(float f){ unsigned u=__float_as_uint(f); return (u&0x80000000u)? ~u : (u|0x80000000u); }
__device__ __forceinline__ float fdec(unsigned k){ return __uint_as_float((k&0x80000000u)? (k^0x80000000u) : ~k); }
__device__ __forceinline__ short f2bf(float f){
    union { float f; unsigned u; } v; v.f = f;
    unsigned r = v.u + 0x7fff + ((v.u >> 16) & 1);   // RNE
    return (short)(r >> 16);
}
__device__ __forceinline__ float bf2f(short s){
    union { unsigned u; float f; } v; v.u = ((unsigned)(unsigned short)s) << 16;
    return v.f;
}

// ---------------- pack a [rows x 128] fp32 weight into MFMA B-fragment bf16 order ----------------
// out[((tile*4+ks)*64+lane)*8+i] = w[(tile*16+(lane&15))*128 + ks*32 + (lane>>4)*8 + i]
__global__ __launch_bounds__(256) void k_pack(const float* __restrict__ w,
                                              short* __restrict__ out, int total)
{
    int idx = blockIdx.x*256 + threadIdx.x;
    if (idx < total){
        int i    = idx & 7;
        int lane = (idx >> 3) & 63;
        int ks   = (idx >> 9) & 3;
        int tile = idx >> 11;
        int row  = tile*16 + (lane & 15);
        int k    = ks*32 + ((lane >> 4) << 3) + i;
        out[idx] = f2bf(w[row*128 + k]);
    }
}

// ---------------- layer 0 node precompute: A16, B16, di ----------------
__global__ __launch_bounds__(256) void k_l0_node(
    const float* __restrict__ x,
    const float* __restrict__ wa, const float* __restrict__ ba,
    const float* __restrict__ wn, const float* __restrict__ bn,
    const float* __restrict__ aw,
    short* __restrict__ A16, short* __restrict__ B16, float* __restrict__ di)
{
    __shared__ float xs[32][40];
    __shared__ float As[32][130];
    const int t = threadIdx.x;
    const int base = blockIdx.x * 32;
    for (int idx = t; idx < 32*39; idx += 256){
        int nn = idx / 39, k = idx - nn*39;
        int node = base + nn;
        xs[nn][k] = (node < NN) ? x[(size_t)node*39 + k] : 0.f;
    }
    __syncthreads();
    const int j = t & 127;
    const int g = t >> 7;
    {
        float accA[16], accB[16];
        #pragma unroll
        for (int nn=0; nn<16; ++nn){ accA[nn]=0.f; accB[nn]=0.f; }
        for (int k=0; k<39; ++k){
            float wva = wa[j*39+k];
            float wvb = wn[j*49+k];
            #pragma unroll
            for (int nn=0; nn<16; ++nn){
                float xv = xs[g*16+nn][k];
                accA[nn] += xv*wva;
                accB[nn] += xv*wvb;
            }
        }
        float bav = ba[j], bnv = bn[j];
        #pragma unroll
        for (int nn=0; nn<16; ++nn){
            int node = base + g*16 + nn;
            float av = lrelu(accA[nn] + bav);
            As[g*16+nn][j] = av;
            if (node < NN){
                A16[(size_t)node*128 + j] = f2bf(av);
                B16[(size_t)node*128 + j] = f2bf(accB[nn] + bnv);
            }
        }
    }
    __syncthreads();
    if (t < 32){
        int node = base + t;
        if (node < NN){
            float d = 0.f;
            for (int k=0; k<128; ++k) d += As[t][k]*aw[k];
            di[node] = d;
        }
    }
}

// ---------------- layer 1 node precompute: di, dj, x16 ----------------
__global__ __launch_bounds__(256) void k_l1_node(
    const float* __restrict__ x1, const float* __restrict__ aw,
    float* __restrict__ di, float* __restrict__ dj, short* __restrict__ x16)
{
    const int node = blockIdx.x*4 + (threadIdx.x >> 6);
    const int lane = threadIdx.x & 63;
    if (node < NN){
        float v0 = x1[(size_t)node*128 + lane];
        float v1 = x1[(size_t)node*128 + 64 + lane];
        x16[(size_t)node*128 + lane]      = f2bf(v0);
        x16[(size_t)node*128 + 64 + lane] = f2bf(v1);
        float pa = v0*aw[lane]     + v1*aw[64+lane];
        float pb = v0*aw[128+lane] + v1*aw[192+lane];
        #pragma unroll
        for (int off=32; off; off>>=1){ pa += __shfl_xor(pa, off); pb += __shfl_xor(pb, off); }
        if (lane == 0){ di[node] = pa; dj[node] = pb; }
    }
}

// ---------------- layer 0 align (per edge) ----------------
#define EPW 8
__global__ __launch_bounds__(256) void k_l0_align(
    const int* __restrict__ srcA, const int* __restrict__ dstA,
    const float* __restrict__ ea,
    const short* __restrict__ B16,
    const float* __restrict__ wn,
    const float* __restrict__ aw, const float* __restrict__ ab,
    const float* __restrict__ di,
    float* __restrict__ evu, unsigned* __restrict__ m)
{
    const int t = threadIdx.x;
    const int lane = t & 63;
    const int w = t >> 6;
    float wn2a[10], wn2b[10];
    #pragma unroll
    for (int k=0; k<10; ++k){
        wn2a[k] = wn[lane*49 + 39 + k];
        wn2b[k] = wn[(lane+64)*49 + 39 + k];
    }
    const float awa = aw[128+lane], awb = aw[128+64+lane];
    const float abv = ab[0];
    const int e0 = (blockIdx.x*4 + w) * EPW;
    for (int i=0; i<EPW; ++i){
        int e = e0 + i;
        int s = srcA[e];
        int d = dstA[e];
        float v1 = bf2f(B16[(size_t)s*128 + lane]);
        float v2 = bf2f(B16[(size_t)s*128 + 64 + lane]);
        #pragma unroll
        for (int k=0; k<10; ++k){
            float ev = ea[(size_t)e*10 + k];
            v1 += ev*wn2a[k];
            v2 += ev*wn2b[k];
        }
        v1 = lrelu(v1); v2 = lrelu(v2);
        float p = v1*awa + v2*awb;
        #pragma unroll
        for (int off=32; off; off>>=1) p += __shfl_xor(p, off);
        if (lane == 0){
            float ev = lrelu(p + di[d] + abv);
            evu[e] = ev;
            atomicMax(m + s, fenc(ev));
        }
    }
}

// ---------------- layer 1 align ----------------
__global__ __launch_bounds__(256) void k_l1_align(
    const int* __restrict__ srcA, const int* __restrict__ dstA,
    const float* __restrict__ di, const float* __restrict__ dj,
    const float* __restrict__ ab,
    float* __restrict__ evu, unsigned* __restrict__ m)
{
    int e = blockIdx.x*256 + threadIdx.x;
    if (e < NE){
        int s = srcA[e], d = dstA[e];
        float v = lrelu(di[d] + dj[s] + ab[0]);
        evu[e] = v;
        atomicMax(m + s, fenc(v));
    }
}

// ---------------- softmax normalize ----------------
__global__ __launch_bounds__(256) void k_norm(
    const int* __restrict__ srcA, const unsigned* __restrict__ m,
    float* __restrict__ ex, float* __restrict__ s)
{
    int e = blockIdx.x*256 + threadIdx.x;
    if (e < NE){
        int sn = srcA[e];
        float v = __expf(ex[e] - fdec(m[sn]));
        ex[e] = v;
        atomicAdd(s + sn, v);
    }
}

// ---------------- heavy per-edge, fully fused ----------------
// 64 edges/block, 512 threads (8 waves). Gather ONLY A16[dst] rows to LDS.
// In-block MFMA: T = A@tw^T+tb ; gh = A@whh^T+bhh ; c = elu(av*T) -> LDS bf16 ;
// gi = c@wih^T+bih ; GRU epilogue all in C-frag registers (hp read from A LDS);
// h staged fp32 in LDS for coalesced atomics.
__global__ __launch_bounds__(512) void k_edge_gru(
    const int* __restrict__ srcA, const int* __restrict__ dstA,
    const float* __restrict__ exA, const float* __restrict__ sA,
    const short* __restrict__ A16,
    const short* __restrict__ twp, const float* __restrict__ tb,
    const short* __restrict__ whhp, const float* __restrict__ bhh,
    const short* __restrict__ wihp, const float* __restrict__ bih,
    float* __restrict__ out)
{
    __shared__ __align__(16) char smem[2*64*272];   // A rows | c rows ; reused as h fp32 [64][132]
    __shared__ int dsts[64];
    __shared__ float av[64];
    char* const A_lds = smem;
    char* const c_lds = smem + 64*272;
    const int t = threadIdx.x;
    const int e0 = blockIdx.x << 6;
    if (t < 64){
        int e = e0 + t;
        int s = srcA[e];
        dsts[t] = dstA[e];
        av[t] = exA[e] / (sA[s] + 1e-16f);
    }
    __syncthreads();
    // ---- gather A16 rows: 64 rows x 256B, 16B per thread x2 ----
    {
        #pragma unroll
        for (int it=0; it<2; ++it){
            int cid = it*512 + t;
            int row = cid >> 4, ch = cid & 15;
            *(int4*)(A_lds + row*272 + ch*16) =
                *(const int4*)(A16 + (size_t)dsts[row]*128 + ch*8);
        }
    }
    __syncthreads();
    const int w = t >> 6;          // wave 0..7 -> cols w*16..w*16+15
    const int lane = t & 63;
    const int l15 = lane & 15;
    const int lhi = lane >> 4;     // 0..3
    const int jb = w*16 + l15;     // output column 0..127
    // ---- T + gh GEMMs from A_lds ----
    f32x4 Tacc[4];
    f32x4 gh[4][3];
    {
        float tbv = tb[jb];
        #pragma unroll
        for (int m=0; m<4; ++m) Tacc[m] = (f32x4){tbv, tbv, tbv, tbv};
        #pragma unroll
        for (int g=0; g<3; ++g){
            float bv = bhh[g*128 + jb];
            #pragma unroll
            for (int m=0; m<4; ++m) gh[m][g] = (f32x4){bv, bv, bv, bv};
        }
    }
    #pragma unroll
    for (int ks=0; ks<4; ++ks){
        bf16x8 af[4];
        #pragma unroll
        for (int m=0; m<4; ++m)
            af[m] = *(const bf16x8*)(A_lds + (m*16+l15)*272 + ks*64 + (lhi<<4));
        bf16x8 tf = *(const bf16x8*)(twp + (size_t)((w*4 + ks)*64 + lane)*8);
        #pragma unroll
        for (int m=0; m<4; ++m)
            Tacc[m] = __builtin_amdgcn_mfma_f32_16x16x32_bf16(af[m], tf, Tacc[m], 0, 0, 0);
        #pragma unroll
        for (int g=0; g<3; ++g){
            bf16x8 wf = *(const bf16x8*)(whhp + (size_t)(((g*8+w)*4 + ks)*64 + lane)*8);
            #pragma unroll
            for (int m=0; m<4; ++m)
                gh[m][g] = __builtin_amdgcn_mfma_f32_16x16x32_bf16(af[m], wf, gh[m][g], 0, 0, 0);
        }
    }
    // ---- c = elu(av*T) -> c_lds bf16 (C-frag: row=m*16+lhi*4+reg, col=jb) ----
    #pragma unroll
    for (int m=0; m<4; ++m){
        #pragma unroll
        for (int reg=0; reg<4; ++reg){
            int e = m*16 + lhi*4 + reg;
            float a = av[e];
            *(short*)(c_lds + e*272 + jb*2) = f2bf(elu1(a * Tacc[m][reg]));
        }
    }
    __syncthreads();
    // ---- gi GEMM from c_lds ----
    f32x4 gi[4][3];
    #pragma unroll
    for (int g=0; g<3; ++g){
        float bv = bih[g*128 + jb];
        #pragma unroll
        for (int m=0; m<4; ++m) gi[m][g] = (f32x4){bv, bv, bv, bv};
    }
    #pragma unroll
    for (int ks=0; ks<4; ++ks){
        bf16x8 cf[4];
        #pragma unroll
        for (int m=0; m<4; ++m)
            cf[m] = *(const bf16x8*)(c_lds + (m*16+l15)*272 + ks*64 + (lhi<<4));
        #pragma unroll
        for (int g=0; g<3; ++g){
            bf16x8 wf = *(const bf16x8*)(wihp + (size_t)(((g*8+w)*4 + ks)*64 + lane)*8);
            #pragma unroll
            for (int m=0; m<4; ++m)
                gi[m][g] = __builtin_amdgcn_mfma_f32_16x16x32_bf16(cf[m], wf, gi[m][g], 0, 0, 0);
        }
    }
    // ---- GRU epilogue fully in registers (hp from A_lds) ----
    float hreg[4][4];
    #pragma unroll
    for (int m=0; m<4; ++m){
        #pragma unroll
        for (int reg=0; reg<4; ++reg){
            int e = m*16 + lhi*4 + reg;
            float hp = bf2f(*(const short*)(A_lds + e*272 + jb*2));
            float r = sigm(gi[m][0][reg] + gh[m][0][reg]);
            float z = sigm(gi[m][1][reg] + gh[m][1][reg]);
            float n = tanh_fast(gi[m][2][reg] + r*gh[m][2][reg]);
            hreg[m][reg] = (1.f - z)*n + z*hp;
        }
    }
    __syncthreads();   // all LDS reads done; smem becomes h[64][132] fp32
    {
        float* hlds = (float*)smem;
        #pragma unroll
        for (int m=0; m<4; ++m){
            #pragma unroll
            for (int reg=0; reg<4; ++reg){
                int e = m*16 + lhi*4 + reg;
                hlds[e*132 + jb] = hreg[m][reg];
            }
        }
    }
    __syncthreads();
    // ---- coalesced scatter-add ----
    {
        const int j = t & 127, eg = t >> 7;        // eg 0..3
        const float* hlds = (const float*)smem;
        #pragma unroll
        for (int el=0; el<16; ++el){
            int e = eg*16 + el;
            atomicAdd(out + (size_t)dsts[e]*128 + j, hlds[e*132 + j]);
        }
    }
}

extern "C" void kernel_launch(void* const* d_in, const int* in_sizes, int n_in,
                              void* d_out, int out_size, void* d_ws, size_t ws_size,
                              hipStream_t stream) {
    const float* x    = (const float*)d_in[0];
    const int*   eidx = (const int*)d_in[1];
    const int*   esrc = eidx;
    const int*   edst = eidx + NE;
    const float* ea   = (const float*)d_in[2];
    const float* a_w  = (const float*)d_in[3];
    const float* a_b  = (const float*)d_in[4];
    const float* n_w  = (const float*)d_in[5];
    const float* n_b  = (const float*)d_in[6];
    const float* al_w0= (const float*)d_in[7];
    const float* al_b0= (const float*)d_in[8];
    const float* t_w0 = (const float*)d_in[9];
    const float* t_b0 = (const float*)d_in[10];
    const float* wih0 = (const float*)d_in[11];
    const float* whh0 = (const float*)d_in[12];
    const float* bih0 = (const float*)d_in[13];
    const float* bhh0 = (const float*)d_in[14];
    const float* al_w1= (const float*)d_in[15];
    const float* al_b1= (const float*)d_in[16];
    const float* t_w1 = (const float*)d_in[17];
    const float* t_b1 = (const float*)d_in[18];
    const float* wih1 = (const float*)d_in[19];
    const float* whh1 = (const float*)d_in[20];
    const float* bih1 = (const float*)d_in[21];
    const float* bhh1 = (const float*)d_in[22];

    float* ws   = (float*)d_ws;
    float* out0 = ws;                               // NN*128
    unsigned* m0 = (unsigned*)(out0 + (size_t)NN*128);
    float*    s0 = (float*)(m0 + NN);
    unsigned* m1 = (unsigned*)(s0 + NN);
    float*    s1 = (float*)(m1 + NN);
    float* evu  = s1 + NN;                          // NE
    float* di   = evu + NE;
    float* dj   = di + NN;
    short* A16  = (short*)(dj + NN);                // NN*128
    short* B16  = A16 + (size_t)NN*128;
    short* x16  = B16 + (size_t)NN*128;
    short* wp0  = x16 + (size_t)NN*128;             // 49152 each
    short* wp1  = wp0 + 49152;
    short* wh0p = wp1 + 49152;
    short* wh1p = wh0p + 49152;
    short* tp0  = wh1p + 49152;                     // 16384 each
    short* tp1  = tp0 + 16384;

    // zero accumulators: out0, m0, s0, m1, s1 contiguous
    hipMemsetAsync(out0, 0, ((size_t)NN*128 + 4*(size_t)NN)*sizeof(float), stream);
    hipMemsetAsync(d_out, 0, (size_t)NN*128*sizeof(float), stream);

    dim3 blk(256);
    k_pack<<<dim3(192), blk, 0, stream>>>(wih0, wp0, 49152);
    k_pack<<<dim3(192), blk, 0, stream>>>(wih1, wp1, 49152);
    k_pack<<<dim3(192), blk, 0, stream>>>(whh0, wh0p, 49152);
    k_pack<<<dim3(192), blk, 0, stream>>>(whh1, wh1p, 49152);
    k_pack<<<dim3(64),  blk, 0, stream>>>(t_w0, tp0, 16384);
    k_pack<<<dim3(64),  blk, 0, stream>>>(t_w1, tp1, 16384);
    // ---- layer 0 ----
    k_l0_node<<<dim3((NN+31)/32), blk, 0, stream>>>(x, a_w, a_b, n_w, n_b, al_w0,
                                                    A16, B16, di);
    k_l0_align<<<dim3(NE/(4*EPW)), blk, 0, stream>>>(esrc, edst, ea, B16, n_w, al_w0, al_b0, di, evu, m0);
    k_norm<<<dim3((NE+255)/256), blk, 0, stream>>>(esrc, m0, evu, s0);
    k_edge_gru<<<dim3(NE/64), dim3(512), 0, stream>>>(esrc, edst, evu, s0, A16,
                                                      tp0, t_b0, wh0p, bhh0, wp0, bih0, out0);
    // ---- layer 1 ----
    k_l1_node<<<dim3((NN+3)/4), blk, 0, stream>>>(out0, al_w1, di, dj, x16);
    k_l1_align<<<dim3((NE+255)/256), blk, 0, stream>>>(esrc, edst, di, dj, al_b1, evu, m1);
    k_norm<<<dim3((NE+255)/256), blk, 0, stream>>>(esrc, m1, evu, s1);
    k_edge_gru<<<dim3(NE/64), dim3(512), 0, stream>>>(esrc, edst, evu, s1, x16,
                                                      tp1, t_b1, wh1p, bhh1, wp1, bih1, (float*)d_out);
}

// Round 5
// 719.285 us; speedup vs baseline: 4.7322x; 1.2569x over previous
//
#include <hip/hip_runtime.h>
#include <hip/hip_bf16.h>
#include <math.h>

#define NN 25000
#define NE 400000

typedef __attribute__((ext_vector_type(8))) short bf16x8;
typedef __attribute__((ext_vector_type(4))) float f32x4;

__device__ __forceinline__ float lrelu(float x){ return x > 0.f ? x : 0.01f*x; }
__device__ __forceinline__ float elu1(float x){ return x > 0.f ? x : (__expf(x)-1.f); }
__device__ __forceinline__ float sigm(float x){ return 1.f/(1.f+__expf(-x)); }
__device__ __forceinline__ float tanh_fast(float x){ float e=__expf(2.f*x); return 1.f - 2.f/(e+1.f); }
__device__ __forceinline__ unsigned fenc(float f){ unsigned u=__float_as_uint(f); return (u&0x80000000u)? ~u : (u|0x80000000u); }
__device__ __forceinline__ float fdec(unsigned k){ return __uint_as_float((k&0x80000000u)? (k^0x80000000u) : ~k); }
__device__ __forceinline__ short f2bf(float f){
    union { float f; unsigned u; } v; v.f = f;
    unsigned r = v.u + 0x7fff + ((v.u >> 16) & 1);   // RNE
    return (short)(r >> 16);
}
__device__ __forceinline__ float bf2f(short s){
    union { unsigned u; float f; } v; v.u = ((unsigned)(unsigned short)s) << 16;
    return v.f;
}

// ---------------- pack a [rows x 128] fp32 weight into MFMA B-fragment bf16 order ----------------
__global__ __launch_bounds__(256) void k_pack(const float* __restrict__ w,
                                              short* __restrict__ out, int total)
{
    int idx = blockIdx.x*256 + threadIdx.x;
    if (idx < total){
        int i    = idx & 7;
        int lane = (idx >> 3) & 63;
        int ks   = (idx >> 9) & 3;
        int tile = idx >> 11;
        int row  = tile*16 + (lane & 15);
        int k    = ks*32 + ((lane >> 4) << 3) + i;
        out[idx] = f2bf(w[row*128 + k]);
    }
}

// ---------------- counting sort by dst ----------------
__global__ __launch_bounds__(256) void k_hist(const int* __restrict__ dst, unsigned* __restrict__ hist)
{
    int e = blockIdx.x*256 + threadIdx.x;
    if (e < NE) atomicAdd(&hist[dst[e]], 1u);
}

__global__ __launch_bounds__(1024) void k_scan(const unsigned* __restrict__ hist,
                                               unsigned* __restrict__ cursor)
{
    __shared__ unsigned ps[1024];
    const int t = threadIdx.x;
    unsigned loc[25]; unsigned sum = 0;
    const int base = t*25;
    #pragma unroll
    for (int i=0;i<25;i++){ int n=base+i; unsigned v=(n<NN)?hist[n]:0u; loc[i]=sum; sum+=v; }
    ps[t]=sum; __syncthreads();
    for (int off=1; off<1024; off<<=1){
        unsigned v = (t>=off)? ps[t-off] : 0u;
        __syncthreads();
        ps[t] += v;
        __syncthreads();
    }
    unsigned bex = (t==0)? 0u : ps[t-1];
    #pragma unroll
    for (int i=0;i<25;i++){ int n=base+i; if(n<NN) cursor[n] = bex + loc[i]; }
}

__global__ __launch_bounds__(256) void k_scatter(const int* __restrict__ dst,
                                                 unsigned* __restrict__ cursor,
                                                 int* __restrict__ se_id, int* __restrict__ se_dst)
{
    int e = blockIdx.x*256 + threadIdx.x;
    if (e < NE){
        int d = dst[e];
        unsigned p = atomicAdd(&cursor[d], 1u);
        se_id[p]  = e;
        se_dst[p] = d;
    }
}

// ---------------- layer 0 node precompute: A16, B16, di ----------------
__global__ __launch_bounds__(256) void k_l0_node(
    const float* __restrict__ x,
    const float* __restrict__ wa, const float* __restrict__ ba,
    const float* __restrict__ wn, const float* __restrict__ bn,
    const float* __restrict__ aw,
    short* __restrict__ A16, short* __restrict__ B16, float* __restrict__ di)
{
    __shared__ float xs[32][40];
    __shared__ float As[32][130];
    const int t = threadIdx.x;
    const int base = blockIdx.x * 32;
    for (int idx = t; idx < 32*39; idx += 256){
        int nn = idx / 39, k = idx - nn*39;
        int node = base + nn;
        xs[nn][k] = (node < NN) ? x[(size_t)node*39 + k] : 0.f;
    }
    __syncthreads();
    const int j = t & 127;
    const int g = t >> 7;
    {
        float accA[16], accB[16];
        #pragma unroll
        for (int nn=0; nn<16; ++nn){ accA[nn]=0.f; accB[nn]=0.f; }
        for (int k=0; k<39; ++k){
            float wva = wa[j*39+k];
            float wvb = wn[j*49+k];
            #pragma unroll
            for (int nn=0; nn<16; ++nn){
                float xv = xs[g*16+nn][k];
                accA[nn] += xv*wva;
                accB[nn] += xv*wvb;
            }
        }
        float bav = ba[j], bnv = bn[j];
        #pragma unroll
        for (int nn=0; nn<16; ++nn){
            int node = base + g*16 + nn;
            float av = lrelu(accA[nn] + bav);
            As[g*16+nn][j] = av;
            if (node < NN){
                A16[(size_t)node*128 + j] = f2bf(av);
                B16[(size_t)node*128 + j] = f2bf(accB[nn] + bnv);
            }
        }
    }
    __syncthreads();
    if (t < 32){
        int node = base + t;
        if (node < NN){
            float d = 0.f;
            for (int k=0; k<128; ++k) d += As[t][k]*aw[k];
            di[node] = d;
        }
    }
}

// ---------------- layer 1 node precompute: di, dj, x16 ----------------
__global__ __launch_bounds__(256) void k_l1_node(
    const float* __restrict__ x1, const float* __restrict__ aw,
    float* __restrict__ di, float* __restrict__ dj, short* __restrict__ x16)
{
    const int node = blockIdx.x*4 + (threadIdx.x >> 6);
    const int lane = threadIdx.x & 63;
    if (node < NN){
        float v0 = x1[(size_t)node*128 + lane];
        float v1 = x1[(size_t)node*128 + 64 + lane];
        x16[(size_t)node*128 + lane]      = f2bf(v0);
        x16[(size_t)node*128 + 64 + lane] = f2bf(v1);
        float pa = v0*aw[lane]     + v1*aw[64+lane];
        float pb = v0*aw[128+lane] + v1*aw[192+lane];
        #pragma unroll
        for (int off=32; off; off>>=1){ pa += __shfl_xor(pa, off); pb += __shfl_xor(pb, off); }
        if (lane == 0){ di[node] = pa; dj[node] = pb; }
    }
}

// ---------------- per-node T/GH tables via MFMA (64 nodes/block) ----------------
__global__ __launch_bounds__(512) void k_node_prep(
    const short* __restrict__ A16,
    const short* __restrict__ twp, const float* __restrict__ tb,
    const short* __restrict__ whhp, const float* __restrict__ bhh,
    short* __restrict__ T16, short* __restrict__ GH16)
{
    __shared__ __align__(16) char A_lds[64*272];
    const int t = threadIdx.x;
    const int base = blockIdx.x << 6;
    #pragma unroll
    for (int it=0; it<2; ++it){
        int cid = it*512 + t;
        int row = cid >> 4, ch = cid & 15;
        int node = base + row; if (node >= NN) node = NN-1;
        *(int4*)(A_lds + row*272 + ch*16) = *(const int4*)(A16 + (size_t)node*128 + ch*8);
    }
    __syncthreads();
    const int w = t >> 6, lane = t & 63;
    const int l15 = lane & 15, lhi = lane >> 4;
    const int jb = w*16 + l15;
    f32x4 Tacc[4], gh[4][3];
    {
        float tbv = tb[jb];
        #pragma unroll
        for (int m=0; m<4; ++m) Tacc[m] = (f32x4){tbv, tbv, tbv, tbv};
        #pragma unroll
        for (int g=0; g<3; ++g){
            float bv = bhh[g*128 + jb];
            #pragma unroll
            for (int m=0; m<4; ++m) gh[m][g] = (f32x4){bv, bv, bv, bv};
        }
    }
    #pragma unroll
    for (int ks=0; ks<4; ++ks){
        bf16x8 af[4];
        #pragma unroll
        for (int m=0; m<4; ++m)
            af[m] = *(const bf16x8*)(A_lds + (m*16+l15)*272 + ks*64 + (lhi<<4));
        bf16x8 tf = *(const bf16x8*)(twp + (size_t)((w*4 + ks)*64 + lane)*8);
        #pragma unroll
        for (int m=0; m<4; ++m)
            Tacc[m] = __builtin_amdgcn_mfma_f32_16x16x32_bf16(af[m], tf, Tacc[m], 0, 0, 0);
        #pragma unroll
        for (int g=0; g<3; ++g){
            bf16x8 wf = *(const bf16x8*)(whhp + (size_t)(((g*8+w)*4 + ks)*64 + lane)*8);
            #pragma unroll
            for (int m=0; m<4; ++m)
                gh[m][g] = __builtin_amdgcn_mfma_f32_16x16x32_bf16(af[m], wf, gh[m][g], 0, 0, 0);
        }
    }
    #pragma unroll
    for (int m=0; m<4; ++m){
        #pragma unroll
        for (int reg=0; reg<4; ++reg){
            int node = base + m*16 + lhi*4 + reg;
            if (node < NN){
                T16[(size_t)node*128 + jb]        = f2bf(Tacc[m][reg]);
                GH16[(size_t)node*384 + jb]       = f2bf(gh[m][0][reg]);
                GH16[(size_t)node*384 + 128 + jb] = f2bf(gh[m][1][reg]);
                GH16[(size_t)node*384 + 256 + jb] = f2bf(gh[m][2][reg]);
            }
        }
    }
}

// ---------------- layer 0 align (per edge) ----------------
#define EPW 8
__global__ __launch_bounds__(256) void k_l0_align(
    const int* __restrict__ srcA, const int* __restrict__ dstA,
    const float* __restrict__ ea,
    const short* __restrict__ B16,
    const float* __restrict__ wn,
    const float* __restrict__ aw, const float* __restrict__ ab,
    const float* __restrict__ di,
    float* __restrict__ evu, unsigned* __restrict__ m)
{
    const int t = threadIdx.x;
    const int lane = t & 63;
    const int w = t >> 6;
    float wn2a[10], wn2b[10];
    #pragma unroll
    for (int k=0; k<10; ++k){
        wn2a[k] = wn[lane*49 + 39 + k];
        wn2b[k] = wn[(lane+64)*49 + 39 + k];
    }
    const float awa = aw[128+lane], awb = aw[128+64+lane];
    const float abv = ab[0];
    const int e0 = (blockIdx.x*4 + w) * EPW;
    for (int i=0; i<EPW; ++i){
        int e = e0 + i;
        int s = srcA[e];
        int d = dstA[e];
        float v1 = bf2f(B16[(size_t)s*128 + lane]);
        float v2 = bf2f(B16[(size_t)s*128 + 64 + lane]);
        #pragma unroll
        for (int k=0; k<10; ++k){
            float ev = ea[(size_t)e*10 + k];
            v1 += ev*wn2a[k];
            v2 += ev*wn2b[k];
        }
        v1 = lrelu(v1); v2 = lrelu(v2);
        float p = v1*awa + v2*awb;
        #pragma unroll
        for (int off=32; off; off>>=1) p += __shfl_xor(p, off);
        if (lane == 0){
            float ev = lrelu(p + di[d] + abv);
            evu[e] = ev;
            atomicMax(m + s, fenc(ev));
        }
    }
}

// ---------------- layer 1 align ----------------
__global__ __launch_bounds__(256) void k_l1_align(
    const int* __restrict__ srcA, const int* __restrict__ dstA,
    const float* __restrict__ di, const float* __restrict__ dj,
    const float* __restrict__ ab,
    float* __restrict__ evu, unsigned* __restrict__ m)
{
    int e = blockIdx.x*256 + threadIdx.x;
    if (e < NE){
        int s = srcA[e], d = dstA[e];
        float v = lrelu(di[d] + dj[s] + ab[0]);
        evu[e] = v;
        atomicMax(m + s, fenc(v));
    }
}

// ---------------- softmax normalize ----------------
__global__ __launch_bounds__(256) void k_norm(
    const int* __restrict__ srcA, const unsigned* __restrict__ m,
    float* __restrict__ ex, float* __restrict__ s)
{
    int e = blockIdx.x*256 + threadIdx.x;
    if (e < NE){
        int sn = srcA[e];
        float v = __expf(ex[e] - fdec(m[sn]));
        ex[e] = v;
        atomicAdd(s + sn, v);
    }
}

// ---------------- heavy per-edge on dst-sorted edges ----------------
// 64 sorted edges/block, 512 threads. Gathers of T16/GH16/HP16 rows are L1/L2-hot
// (consecutive edges share dst). Single gi GEMM; scatter-add run-compressed.
__global__ __launch_bounds__(512) void k_edge_gru(
    const int* __restrict__ srcA,
    const int* __restrict__ se_id, const int* __restrict__ se_dst,
    const float* __restrict__ exA, const float* __restrict__ sA,
    const short* __restrict__ T16, const short* __restrict__ GH16,
    const short* __restrict__ HP16,
    const short* __restrict__ wihp, const float* __restrict__ bih,
    float* __restrict__ out)
{
    __shared__ __align__(16) char smem[64*132*4];   // c bf16 [64][272B] ; reused as h fp32 [64][132]
    __shared__ int dsts[64];
    __shared__ float av[64];
    char* const c_lds = smem;
    const int t = threadIdx.x;
    const int p0 = blockIdx.x << 6;
    if (t < 64){
        int p = p0 + t;
        int eid = se_id[p];
        dsts[t] = se_dst[p];
        av[t] = exA[eid] / (sA[srcA[eid]] + 1e-16f);
    }
    __syncthreads();
    // ---- c = elu(av * T16[dst]) -> c_lds bf16 ----
    #pragma unroll
    for (int it=0; it<2; ++it){
        int cid = it*512 + t;
        int row = cid >> 4, ch = cid & 15;
        int d = dsts[row];
        float a = av[row];
        bf16x8 tv = *(const bf16x8*)(T16 + (size_t)d*128 + ch*8);
        union { short s[8]; int4 v; } u;
        #pragma unroll
        for (int i=0; i<8; ++i) u.s[i] = f2bf(elu1(a * bf2f(tv[i])));
        *(int4*)(c_lds + row*272 + ch*16) = u.v;
    }
    __syncthreads();
    const int w = t >> 6, lane = t & 63;
    const int l15 = lane & 15, lhi = lane >> 4;
    const int jb = w*16 + l15;
    // ---- gi GEMM ----
    f32x4 gi[4][3];
    #pragma unroll
    for (int g=0; g<3; ++g){
        float bv = bih[g*128 + jb];
        #pragma unroll
        for (int m=0; m<4; ++m) gi[m][g] = (f32x4){bv, bv, bv, bv};
    }
    #pragma unroll
    for (int ks=0; ks<4; ++ks){
        bf16x8 cf[4];
        #pragma unroll
        for (int m=0; m<4; ++m)
            cf[m] = *(const bf16x8*)(c_lds + (m*16+l15)*272 + ks*64 + (lhi<<4));
        #pragma unroll
        for (int g=0; g<3; ++g){
            bf16x8 wf = *(const bf16x8*)(wihp + (size_t)(((g*8+w)*4 + ks)*64 + lane)*8);
            #pragma unroll
            for (int m=0; m<4; ++m)
                gi[m][g] = __builtin_amdgcn_mfma_f32_16x16x32_bf16(cf[m], wf, gi[m][g], 0, 0, 0);
        }
    }
    // ---- GRU epilogue (gh/hp gathered bf16, L1-hot due to sorting) ----
    float hreg[4][4];
    #pragma unroll
    for (int m=0; m<4; ++m){
        #pragma unroll
        for (int reg=0; reg<4; ++reg){
            int e = m*16 + lhi*4 + reg;
            int d = dsts[e];
            const short* gh = GH16 + (size_t)d*384;
            float r = sigm(gi[m][0][reg] + bf2f(gh[jb]));
            float z = sigm(gi[m][1][reg] + bf2f(gh[128+jb]));
            float n = tanh_fast(gi[m][2][reg] + r*bf2f(gh[256+jb]));
            float hp = bf2f(HP16[(size_t)d*128 + jb]);
            hreg[m][reg] = (1.f - z)*n + z*hp;
        }
    }
    __syncthreads();   // c reads done; smem becomes h[64][132] fp32
    {
        float* hlds = (float*)smem;
        #pragma unroll
        for (int m=0; m<4; ++m){
            #pragma unroll
            for (int reg=0; reg<4; ++reg){
                int e = m*16 + lhi*4 + reg;
                hlds[e*132 + jb] = hreg[m][reg];
            }
        }
    }
    __syncthreads();
    // ---- run-compressed scatter-add (sorted dst -> few atomics) ----
    {
        const int j = t & 127, eg = t >> 7;    // each thread: 16 consecutive sorted edges
        const float* hlds = (const float*)smem;
        float acc = 0.f; int prev = -1;
        #pragma unroll
        for (int el=0; el<16; ++el){
            int e = eg*16 + el;
            int d = dsts[e];
            float v = hlds[e*132 + j];
            if (d == prev) acc += v;
            else {
                if (prev >= 0) atomicAdd(out + (size_t)prev*128 + j, acc);
                acc = v; prev = d;
            }
        }
        atomicAdd(out + (size_t)prev*128 + j, acc);
    }
}

extern "C" void kernel_launch(void* const* d_in, const int* in_sizes, int n_in,
                              void* d_out, int out_size, void* d_ws, size_t ws_size,
                              hipStream_t stream) {
    const float* x    = (const float*)d_in[0];
    const int*   eidx = (const int*)d_in[1];
    const int*   esrc = eidx;
    const int*   edst = eidx + NE;
    const float* ea   = (const float*)d_in[2];
    const float* a_w  = (const float*)d_in[3];
    const float* a_b  = (const float*)d_in[4];
    const float* n_w  = (const float*)d_in[5];
    const float* n_b  = (const float*)d_in[6];
    const float* al_w0= (const float*)d_in[7];
    const float* al_b0= (const float*)d_in[8];
    const float* t_w0 = (const float*)d_in[9];
    const float* t_b0 = (const float*)d_in[10];
    const float* wih0 = (const float*)d_in[11];
    const float* whh0 = (const float*)d_in[12];
    const float* bih0 = (const float*)d_in[13];
    const float* bhh0 = (const float*)d_in[14];
    const float* al_w1= (const float*)d_in[15];
    const float* al_b1= (const float*)d_in[16];
    const float* t_w1 = (const float*)d_in[17];
    const float* t_b1 = (const float*)d_in[18];
    const float* wih1 = (const float*)d_in[19];
    const float* whh1 = (const float*)d_in[20];
    const float* bih1 = (const float*)d_in[21];
    const float* bhh1 = (const float*)d_in[22];

    float* ws   = (float*)d_ws;
    float* out0 = ws;                               // NN*128 f
    unsigned* m0 = (unsigned*)(out0 + (size_t)NN*128);
    float*    s0 = (float*)(m0 + NN);
    unsigned* m1 = (unsigned*)(s0 + NN);
    float*    s1 = (float*)(m1 + NN);
    float* evu  = s1 + NN;                          // NE f
    float* di   = evu + NE;
    float* dj   = di + NN;
    unsigned* hist   = (unsigned*)(dj + NN);        // NN
    unsigned* cursor = hist + NN;                   // NN
    int* se_id  = (int*)(cursor + NN);              // NE
    int* se_dst = se_id + NE;                       // NE
    short* A16  = (short*)(se_dst + NE);            // NN*128
    short* BX16 = A16 + (size_t)NN*128;             // B16 (l0) then x16 (l1)
    short* T16  = BX16 + (size_t)NN*128;            // NN*128
    short* GH16 = T16 + (size_t)NN*128;             // NN*384
    short* wp0  = GH16 + (size_t)NN*384;            // 49152 each
    short* wp1  = wp0 + 49152;
    short* wh0p = wp1 + 49152;
    short* wh1p = wh0p + 49152;
    short* tp0  = wh1p + 49152;                     // 16384 each
    short* tp1  = tp0 + 16384;

    // zero accumulators (out0, m0, s0, m1, s1 contiguous) + d_out + hist
    hipMemsetAsync(out0, 0, ((size_t)NN*128 + 4*(size_t)NN)*sizeof(float), stream);
    hipMemsetAsync(d_out, 0, (size_t)NN*128*sizeof(float), stream);
    hipMemsetAsync(hist, 0, (size_t)NN*sizeof(unsigned), stream);

    dim3 blk(256);
    // weight packs
    k_pack<<<dim3(192), blk, 0, stream>>>(wih0, wp0, 49152);
    k_pack<<<dim3(192), blk, 0, stream>>>(wih1, wp1, 49152);
    k_pack<<<dim3(192), blk, 0, stream>>>(whh0, wh0p, 49152);
    k_pack<<<dim3(192), blk, 0, stream>>>(whh1, wh1p, 49152);
    k_pack<<<dim3(64),  blk, 0, stream>>>(t_w0, tp0, 16384);
    k_pack<<<dim3(64),  blk, 0, stream>>>(t_w1, tp1, 16384);
    // sort edges by dst (shared across both layers)
    k_hist<<<dim3((NE+255)/256), blk, 0, stream>>>(edst, hist);
    k_scan<<<dim3(1), dim3(1024), 0, stream>>>(hist, cursor);
    k_scatter<<<dim3((NE+255)/256), blk, 0, stream>>>(edst, cursor, se_id, se_dst);
    // ---- layer 0 ----
    k_l0_node<<<dim3((NN+31)/32), blk, 0, stream>>>(x, a_w, a_b, n_w, n_b, al_w0,
                                                    A16, BX16, di);
    k_node_prep<<<dim3((NN+63)/64), dim3(512), 0, stream>>>(A16, tp0, t_b0, wh0p, bhh0, T16, GH16);
    k_l0_align<<<dim3(NE/(4*EPW)), blk, 0, stream>>>(esrc, edst, ea, BX16, n_w, al_w0, al_b0, di, evu, m0);
    k_norm<<<dim3((NE+255)/256), blk, 0, stream>>>(esrc, m0, evu, s0);
    k_edge_gru<<<dim3(NE/64), dim3(512), 0, stream>>>(esrc, se_id, se_dst, evu, s0,
                                                      T16, GH16, A16, wp0, bih0, out0);
    // ---- layer 1 ----
    k_l1_node<<<dim3((NN+3)/4), blk, 0, stream>>>(out0, al_w1, di, dj, BX16);
    k_node_prep<<<dim3((NN+63)/64), dim3(512), 0, stream>>>(BX16, tp1, t_b1, wh1p, bhh1, T16, GH16);
    k_l1_align<<<dim3((NE+255)/256), blk, 0, stream>>>(esrc, edst, di, dj, al_b1, evu, m1);
    k_norm<<<dim3((NE+255)/256), blk, 0, stream>>>(esrc, m1, evu, s1);
    k_edge_gru<<<dim3(NE/64), dim3(512), 0, stream>>>(esrc, se_id, se_dst, evu, s1,
                                                      T16, GH16, BX16, wp1, bih1, (float*)d_out);
}

// Round 6
// 648.420 us; speedup vs baseline: 5.2494x; 1.1093x over previous
//
#include <hip/hip_runtime.h>
#include <math.h>

#define NN 25000
#define NE 400000
#define NINF -1e30f

typedef __attribute__((ext_vector_type(8))) short bf16x8;
typedef __attribute__((ext_vector_type(4))) float f32x4;

__device__ __forceinline__ float lrelu(float x){ return x > 0.f ? x : 0.01f*x; }
__device__ __forceinline__ float elu1(float x){ return x > 0.f ? x : (__expf(x)-1.f); }
__device__ __forceinline__ float sigm(float x){ return 1.f/(1.f+__expf(-x)); }
__device__ __forceinline__ float tanh_fast(float x){ float e=__expf(2.f*x); return 1.f - 2.f/(e+1.f); }
__device__ __forceinline__ short f2bf(float f){
    union { float f; unsigned u; } v; v.f = f;
    unsigned r = v.u + 0x7fff + ((v.u >> 16) & 1);   // RNE
    return (short)(r >> 16);
}
__device__ __forceinline__ float bf2f(short s){
    union { unsigned u; float f; } v; v.u = ((unsigned)(unsigned short)s) << 16;
    return v.f;
}

// ---------------- pack all 6 [rowsx128] fp32 weights into MFMA B-frag bf16 order ----------------
// sections: wih0(192 blk), wih1(192), whh0(192), whh1(192), tw0(64), tw1(64) = 896 blocks
__global__ __launch_bounds__(256) void k_pack6(
    const float* __restrict__ w0, const float* __restrict__ w1,
    const float* __restrict__ w2, const float* __restrict__ w3,
    const float* __restrict__ w4, const float* __restrict__ w5,
    short* __restrict__ o0, short* __restrict__ o1, short* __restrict__ o2,
    short* __restrict__ o3, short* __restrict__ o4, short* __restrict__ o5)
{
    int b = blockIdx.x;
    const float* w; short* o; int idx;
    if      (b < 192){ w=w0; o=o0; idx = b*256; }
    else if (b < 384){ w=w1; o=o1; idx = (b-192)*256; }
    else if (b < 576){ w=w2; o=o2; idx = (b-384)*256; }
    else if (b < 768){ w=w3; o=o3; idx = (b-576)*256; }
    else if (b < 832){ w=w4; o=o4; idx = (b-768)*256; }
    else             { w=w5; o=o5; idx = (b-832)*256; }
    idx += threadIdx.x;
    int i    = idx & 7;
    int lane = (idx >> 3) & 63;
    int ks   = (idx >> 9) & 3;
    int tile = idx >> 11;
    int row  = tile*16 + (lane & 15);
    int k    = ks*32 + ((lane >> 4) << 3) + i;
    o[idx] = f2bf(w[row*128 + k]);
}

// ---------------- dual histogram (dst + src) ----------------
__global__ __launch_bounds__(256) void k_hist2(const int* __restrict__ src,
                                               const int* __restrict__ dst,
                                               unsigned* __restrict__ hd,
                                               unsigned* __restrict__ hs)
{
    int e = blockIdx.x*256 + threadIdx.x;
    if (e < NE){
        atomicAdd(&hd[dst[e]], 1u);
        atomicAdd(&hs[src[e]], 1u);
    }
}

// ---------------- dual exclusive scan: block 0 -> cursor_dst ; block 1 -> cursor_src + srcptr ----------------
__global__ __launch_bounds__(1024) void k_scan2(
    const unsigned* __restrict__ hd, unsigned* __restrict__ cd,
    const unsigned* __restrict__ hs, unsigned* __restrict__ cs,
    int* __restrict__ srcptr)
{
    __shared__ unsigned ps[1024];
    const int issrc = blockIdx.x;
    const unsigned* h = issrc ? hs : hd;
    unsigned* c = issrc ? cs : cd;
    const int t = threadIdx.x;
    unsigned loc[25]; unsigned sum = 0;
    const int base = t*25;
    #pragma unroll
    for (int i=0;i<25;i++){ int n=base+i; unsigned v=(n<NN)?h[n]:0u; loc[i]=sum; sum+=v; }
    ps[t]=sum; __syncthreads();
    for (int off=1; off<1024; off<<=1){
        unsigned v = (t>=off)? ps[t-off] : 0u;
        __syncthreads();
        ps[t] += v;
        __syncthreads();
    }
    unsigned bex = (t==0)? 0u : ps[t-1];
    #pragma unroll
    for (int i=0;i<25;i++){
        int n=base+i;
        if (n<NN){
            unsigned off = bex + loc[i];
            c[n] = off;
            if (issrc) srcptr[n] = (int)off;
        }
    }
    if (issrc && t==1023) srcptr[NN] = NE;
}

// ---------------- dual scatter: dst-order (se_dst + inv map) and src-order (se2_id/se2_dst) ----------------
__global__ __launch_bounds__(256) void k_scatter2(
    const int* __restrict__ src, const int* __restrict__ dst,
    unsigned* __restrict__ cd, unsigned* __restrict__ cs,
    int* __restrict__ se_dst, int* __restrict__ inv_dst,
    int* __restrict__ se2_id, int* __restrict__ se2_dst)
{
    int e = blockIdx.x*256 + threadIdx.x;
    if (e < NE){
        int d = dst[e], s = src[e];
        unsigned p = atomicAdd(&cd[d], 1u);
        se_dst[p] = d;
        inv_dst[e] = (int)p;
        unsigned q = atomicAdd(&cs[s], 1u);
        se2_id[q] = e;
        se2_dst[q] = d;
    }
}

// ---------------- layer 0 node precompute: A16, B16, di ----------------
__global__ __launch_bounds__(256) void k_l0_node(
    const float* __restrict__ x,
    const float* __restrict__ wa, const float* __restrict__ ba,
    const float* __restrict__ wn, const float* __restrict__ bn,
    const float* __restrict__ aw,
    short* __restrict__ A16, short* __restrict__ B16, float* __restrict__ di)
{
    __shared__ float xs[32][40];
    __shared__ float As[32][130];
    const int t = threadIdx.x;
    const int base = blockIdx.x * 32;
    for (int idx = t; idx < 32*39; idx += 256){
        int nn = idx / 39, k = idx - nn*39;
        int node = base + nn;
        xs[nn][k] = (node < NN) ? x[(size_t)node*39 + k] : 0.f;
    }
    __syncthreads();
    const int j = t & 127;
    const int g = t >> 7;
    {
        float accA[16], accB[16];
        #pragma unroll
        for (int nn=0; nn<16; ++nn){ accA[nn]=0.f; accB[nn]=0.f; }
        for (int k=0; k<39; ++k){
            float wva = wa[j*39+k];
            float wvb = wn[j*49+k];
            #pragma unroll
            for (int nn=0; nn<16; ++nn){
                float xv = xs[g*16+nn][k];
                accA[nn] += xv*wva;
                accB[nn] += xv*wvb;
            }
        }
        float bav = ba[j], bnv = bn[j];
        #pragma unroll
        for (int nn=0; nn<16; ++nn){
            int node = base + g*16 + nn;
            float av = lrelu(accA[nn] + bav);
            As[g*16+nn][j] = av;
            if (node < NN){
                A16[(size_t)node*128 + j] = f2bf(av);
                B16[(size_t)node*128 + j] = f2bf(accB[nn] + bnv);
            }
        }
    }
    __syncthreads();
    if (t < 32){
        int node = base + t;
        if (node < NN){
            float d = 0.f;
            for (int k=0; k<128; ++k) d += As[t][k]*aw[k];
            di[node] = d;
        }
    }
}

// ---------------- per-node T/GH tables via MFMA (64 nodes/block), layer 0 ----------------
__global__ __launch_bounds__(512) void k_node_prep(
    const short* __restrict__ A16,
    const short* __restrict__ twp, const float* __restrict__ tb,
    const short* __restrict__ whhp, const float* __restrict__ bhh,
    short* __restrict__ T16, short* __restrict__ GH16)
{
    __shared__ __align__(16) char A_lds[64*272];
    const int t = threadIdx.x;
    const int base = blockIdx.x << 6;
    #pragma unroll
    for (int it=0; it<2; ++it){
        int cid = it*512 + t;
        int row = cid >> 4, ch = cid & 15;
        int node = base + row; if (node >= NN) node = NN-1;
        *(int4*)(A_lds + row*272 + ch*16) = *(const int4*)(A16 + (size_t)node*128 + ch*8);
    }
    __syncthreads();
    const int w = t >> 6, lane = t & 63;
    const int l15 = lane & 15, lhi = lane >> 4;
    const int jb = w*16 + l15;
    f32x4 Tacc[4], gh[4][3];
    {
        float tbv = tb[jb];
        #pragma unroll
        for (int m=0; m<4; ++m) Tacc[m] = (f32x4){tbv, tbv, tbv, tbv};
        #pragma unroll
        for (int g=0; g<3; ++g){
            float bv = bhh[g*128 + jb];
            #pragma unroll
            for (int m=0; m<4; ++m) gh[m][g] = (f32x4){bv, bv, bv, bv};
        }
    }
    #pragma unroll
    for (int ks=0; ks<4; ++ks){
        bf16x8 af[4];
        #pragma unroll
        for (int m=0; m<4; ++m)
            af[m] = *(const bf16x8*)(A_lds + (m*16+l15)*272 + ks*64 + (lhi<<4));
        bf16x8 tf = *(const bf16x8*)(twp + (size_t)((w*4 + ks)*64 + lane)*8);
        #pragma unroll
        for (int m=0; m<4; ++m)
            Tacc[m] = __builtin_amdgcn_mfma_f32_16x16x32_bf16(af[m], tf, Tacc[m], 0, 0, 0);
        #pragma unroll
        for (int g=0; g<3; ++g){
            bf16x8 wf = *(const bf16x8*)(whhp + (size_t)(((g*8+w)*4 + ks)*64 + lane)*8);
            #pragma unroll
            for (int m=0; m<4; ++m)
                gh[m][g] = __builtin_amdgcn_mfma_f32_16x16x32_bf16(af[m], wf, gh[m][g], 0, 0, 0);
        }
    }
    #pragma unroll
    for (int m=0; m<4; ++m){
        #pragma unroll
        for (int reg=0; reg<4; ++reg){
            int node = base + m*16 + lhi*4 + reg;
            if (node < NN){
                T16[(size_t)node*128 + jb]        = f2bf(Tacc[m][reg]);
                GH16[(size_t)node*384 + jb]       = f2bf(gh[m][0][reg]);
                GH16[(size_t)node*384 + 128 + jb] = f2bf(gh[m][1][reg]);
                GH16[(size_t)node*384 + 256 + jb] = f2bf(gh[m][2][reg]);
            }
        }
    }
}

// ---------------- layer 1 prep: out0 -> x16 (+LDS), di, dj, T16, GH16 (merged) ----------------
__global__ __launch_bounds__(512) void k_l1_prep(
    const float* __restrict__ out0, const float* __restrict__ aw,
    const short* __restrict__ twp, const float* __restrict__ tb,
    const short* __restrict__ whhp, const float* __restrict__ bhh,
    short* __restrict__ x16, float* __restrict__ di, float* __restrict__ dj,
    short* __restrict__ T16, short* __restrict__ GH16)
{
    __shared__ __align__(16) char x_lds[64*272];
    const int t = threadIdx.x;
    const int base = blockIdx.x << 6;
    {
        int r = t >> 3, c0 = (t & 7) * 16;
        int node = base + r;
        int nc = node < NN ? node : NN-1;
        const float4* sp = (const float4*)(out0 + (size_t)nc*128 + c0);
        float4 f0 = sp[0], f1 = sp[1], f2 = sp[2], f3 = sp[3];
        union { short s[16]; int4 v[2]; } u;
        u.s[0]=f2bf(f0.x); u.s[1]=f2bf(f0.y); u.s[2]=f2bf(f0.z); u.s[3]=f2bf(f0.w);
        u.s[4]=f2bf(f1.x); u.s[5]=f2bf(f1.y); u.s[6]=f2bf(f1.z); u.s[7]=f2bf(f1.w);
        u.s[8]=f2bf(f2.x); u.s[9]=f2bf(f2.y); u.s[10]=f2bf(f2.z); u.s[11]=f2bf(f2.w);
        u.s[12]=f2bf(f3.x); u.s[13]=f2bf(f3.y); u.s[14]=f2bf(f3.z); u.s[15]=f2bf(f3.w);
        *(int4*)(x_lds + r*272 + c0*2)      = u.v[0];
        *(int4*)(x_lds + r*272 + c0*2 + 16) = u.v[1];
        if (node < NN){
            *(int4*)(x16 + (size_t)node*128 + c0)     = u.v[0];
            *(int4*)(x16 + (size_t)node*128 + c0 + 8) = u.v[1];
        }
    }
    __syncthreads();
    const int w = t >> 6, lane = t & 63;
    {   // di/dj: wave w handles rows w*8..w*8+7
        float a0 = aw[lane], a1 = aw[64+lane], a2 = aw[128+lane], a3 = aw[192+lane];
        for (int i=0;i<8;++i){
            int r = w*8 + i;
            int node = base + r;
            float v0 = bf2f(*(const short*)(x_lds + r*272 + lane*2));
            float v1 = bf2f(*(const short*)(x_lds + r*272 + 128 + lane*2));
            float pa = v0*a0 + v1*a1;
            float pb = v0*a2 + v1*a3;
            #pragma unroll
            for (int off=32; off; off>>=1){ pa += __shfl_xor(pa,off); pb += __shfl_xor(pb,off); }
            if (lane==0 && node<NN){ di[node]=pa; dj[node]=pb; }
        }
    }
    const int l15 = lane & 15, lhi = lane >> 4;
    const int jb = w*16 + l15;
    f32x4 Tacc[4], gh[4][3];
    {
        float tbv = tb[jb];
        #pragma unroll
        for (int m=0; m<4; ++m) Tacc[m] = (f32x4){tbv, tbv, tbv, tbv};
        #pragma unroll
        for (int g=0; g<3; ++g){
            float bv = bhh[g*128 + jb];
            #pragma unroll
            for (int m=0; m<4; ++m) gh[m][g] = (f32x4){bv, bv, bv, bv};
        }
    }
    #pragma unroll
    for (int ks=0; ks<4; ++ks){
        bf16x8 af[4];
        #pragma unroll
        for (int m=0; m<4; ++m)
            af[m] = *(const bf16x8*)(x_lds + (m*16+l15)*272 + ks*64 + (lhi<<4));
        bf16x8 tf = *(const bf16x8*)(twp + (size_t)((w*4 + ks)*64 + lane)*8);
        #pragma unroll
        for (int m=0; m<4; ++m)
            Tacc[m] = __builtin_amdgcn_mfma_f32_16x16x32_bf16(af[m], tf, Tacc[m], 0, 0, 0);
        #pragma unroll
        for (int g=0; g<3; ++g){
            bf16x8 wf = *(const bf16x8*)(whhp + (size_t)(((g*8+w)*4 + ks)*64 + lane)*8);
            #pragma unroll
            for (int m=0; m<4; ++m)
                gh[m][g] = __builtin_amdgcn_mfma_f32_16x16x32_bf16(af[m], wf, gh[m][g], 0, 0, 0);
        }
    }
    #pragma unroll
    for (int m=0; m<4; ++m){
        #pragma unroll
        for (int reg=0; reg<4; ++reg){
            int node = base + m*16 + lhi*4 + reg;
            if (node < NN){
                T16[(size_t)node*128 + jb]        = f2bf(Tacc[m][reg]);
                GH16[(size_t)node*384 + jb]       = f2bf(gh[m][0][reg]);
                GH16[(size_t)node*384 + 128 + jb] = f2bf(gh[m][1][reg]);
                GH16[(size_t)node*384 + 256 + jb] = f2bf(gh[m][2][reg]);
            }
        }
    }
}

// ---------------- fused align+softmax, layer 0 (one wave per src node, no atomics) ----------------
__global__ __launch_bounds__(256) void k_align0(
    const int* __restrict__ srcptr, const int* __restrict__ se2_id,
    const int* __restrict__ se2_dst, const int* __restrict__ inv_dst,
    const float* __restrict__ ea, const short* __restrict__ B16,
    const float* __restrict__ wn, const float* __restrict__ aw,
    const float* __restrict__ ab, const float* __restrict__ di,
    float* __restrict__ evu_tmp, float* __restrict__ avu)
{
    const int lane = threadIdx.x & 63;
    const int node = blockIdx.x*4 + (threadIdx.x >> 6);
    if (node >= NN) return;
    const int start = srcptr[node], end = srcptr[node+1];
    if (start >= end) return;
    float wn2a[10], wn2b[10];
    #pragma unroll
    for (int k=0;k<10;++k){
        wn2a[k] = wn[lane*49 + 39 + k];
        wn2b[k] = wn[(lane+64)*49 + 39 + k];
    }
    const float awa = aw[128+lane], awb = aw[192+lane];
    const float abv = ab[0];
    const float v1b = bf2f(B16[(size_t)node*128 + lane]);
    const float v2b = bf2f(B16[(size_t)node*128 + 64 + lane]);
    const int deg = end - start;
    if (deg <= 64){
        int myeid = 0; float mydi = 0.f; float ear[10];
        if (lane < deg){
            int pos = start + lane;
            myeid = se2_id[pos];
            mydi  = di[se2_dst[pos]];
            #pragma unroll
            for (int k=0;k<10;++k) ear[k] = ea[(size_t)myeid*10 + k];
        }
        float pv = NINF;
        for (int i=0;i<deg;++i){
            float v1 = v1b, v2 = v2b;
            #pragma unroll
            for (int k=0;k<10;++k){
                float e = __shfl(ear[k], i);
                v1 += e*wn2a[k]; v2 += e*wn2b[k];
            }
            v1 = lrelu(v1); v2 = lrelu(v2);
            float p = v1*awa + v2*awb;
            #pragma unroll
            for (int off=32; off; off>>=1) p += __shfl_xor(p, off);
            float pe = lrelu(p + __shfl(mydi, i) + abv);
            if (lane == i) pv = pe;
        }
        float cm = pv;
        #pragma unroll
        for (int off=32; off; off>>=1) cm = fmaxf(cm, __shfl_xor(cm, off));
        float ex = (lane < deg) ? __expf(pv - cm) : 0.f;
        float cs = ex;
        #pragma unroll
        for (int off=32; off; off>>=1) cs += __shfl_xor(cs, off);
        if (lane < deg) avu[inv_dst[myeid]] = ex / (cs + 1e-16f);
    } else {
        float mrun = NINF, srun = 0.f;
        for (int c0 = start; c0 < end; c0 += 64){
            int nE = min(64, end - c0);
            int myeid=0; float mydi=0.f; float ear[10];
            if (lane < nE){
                int pos = c0 + lane;
                myeid = se2_id[pos];
                mydi = di[se2_dst[pos]];
                #pragma unroll
                for (int k=0;k<10;++k) ear[k] = ea[(size_t)myeid*10 + k];
            }
            float pv = NINF;
            for (int i=0;i<nE;++i){
                float v1=v1b, v2=v2b;
                #pragma unroll
                for (int k=0;k<10;++k){
                    float e = __shfl(ear[k], i);
                    v1 += e*wn2a[k]; v2 += e*wn2b[k];
                }
                v1=lrelu(v1); v2=lrelu(v2);
                float p = v1*awa + v2*awb;
                #pragma unroll
                for (int off=32; off; off>>=1) p += __shfl_xor(p, off);
                float pe = lrelu(p + __shfl(mydi,i) + abv);
                if (lane == i) pv = pe;
            }
            if (lane < nE) evu_tmp[c0+lane] = pv;
            float cm = pv;
            #pragma unroll
            for (int off=32; off; off>>=1) cm = fmaxf(cm, __shfl_xor(cm,off));
            float nm = fmaxf(mrun, cm);
            float exs = (lane<nE)? __expf(pv-nm) : 0.f;
            float cs = exs;
            #pragma unroll
            for (int off=32; off; off>>=1) cs += __shfl_xor(cs, off);
            srun = srun*__expf(mrun-nm) + cs;
            mrun = nm;
        }
        float inv = 1.f/(srun + 1e-16f);
        for (int c0 = start; c0 < end; c0 += 64){
            int nE = min(64, end - c0);
            if (lane < nE){
                int pos = c0+lane;
                float pv = evu_tmp[pos];
                avu[inv_dst[se2_id[pos]]] = __expf(pv - mrun)*inv;
            }
        }
    }
}

// ---------------- fused align+softmax, layer 1 ----------------
__global__ __launch_bounds__(256) void k_align1(
    const int* __restrict__ srcptr, const int* __restrict__ se2_id,
    const int* __restrict__ se2_dst, const int* __restrict__ inv_dst,
    const float* __restrict__ di, const float* __restrict__ dj,
    const float* __restrict__ ab,
    float* __restrict__ evu_tmp, float* __restrict__ avu)
{
    const int lane = threadIdx.x & 63;
    const int node = blockIdx.x*4 + (threadIdx.x >> 6);
    if (node >= NN) return;
    const int start = srcptr[node], end = srcptr[node+1];
    if (start >= end) return;
    const float djs = dj[node] + ab[0];
    const int deg = end - start;
    if (deg <= 64){
        int myeid = 0; float pv = NINF;
        if (lane < deg){
            int pos = start + lane;
            myeid = se2_id[pos];
            pv = lrelu(di[se2_dst[pos]] + djs);
        }
        float cm = pv;
        #pragma unroll
        for (int off=32; off; off>>=1) cm = fmaxf(cm, __shfl_xor(cm, off));
        float ex = (lane < deg) ? __expf(pv - cm) : 0.f;
        float cs = ex;
        #pragma unroll
        for (int off=32; off; off>>=1) cs += __shfl_xor(cs, off);
        if (lane < deg) avu[inv_dst[myeid]] = ex / (cs + 1e-16f);
    } else {
        float mrun = NINF, srun = 0.f;
        for (int c0 = start; c0 < end; c0 += 64){
            int nE = min(64, end - c0);
            float pv = NINF;
            if (lane < nE){
                int pos = c0 + lane;
                pv = lrelu(di[se2_dst[pos]] + djs);
                evu_tmp[pos] = pv;
            }
            float cm = pv;
            #pragma unroll
            for (int off=32; off; off>>=1) cm = fmaxf(cm, __shfl_xor(cm,off));
            float nm = fmaxf(mrun, cm);
            float exs = (lane<nE)? __expf(pv-nm) : 0.f;
            float cs = exs;
            #pragma unroll
            for (int off=32; off; off>>=1) cs += __shfl_xor(cs, off);
            srun = srun*__expf(mrun-nm) + cs;
            mrun = nm;
        }
        float inv = 1.f/(srun + 1e-16f);
        for (int c0 = start; c0 < end; c0 += 64){
            int nE = min(64, end - c0);
            if (lane < nE){
                int pos = c0+lane;
                avu[inv_dst[se2_id[pos]]] = __expf(evu_tmp[pos] - mrun)*inv;
            }
        }
    }
}

// ---------------- heavy per-edge on dst-sorted edges ----------------
__global__ __launch_bounds__(512) void k_edge_gru(
    const int* __restrict__ se_dst,
    const float* __restrict__ avu,
    const short* __restrict__ T16, const short* __restrict__ GH16,
    const short* __restrict__ HP16,
    const short* __restrict__ wihp, const float* __restrict__ bih,
    float* __restrict__ out)
{
    __shared__ __align__(16) char smem[64*132*4];   // c bf16 [64][272B] ; reused as h fp32 [64][132]
    __shared__ int dsts[64];
    __shared__ float av[64];
    char* const c_lds = smem;
    const int t = threadIdx.x;
    const int p0 = blockIdx.x << 6;
    if (t < 64){
        dsts[t] = se_dst[p0 + t];
        av[t] = avu[p0 + t];
    }
    __syncthreads();
    // ---- c = elu(av * T16[dst]) -> c_lds bf16 ----
    #pragma unroll
    for (int it=0; it<2; ++it){
        int cid = it*512 + t;
        int row = cid >> 4, ch = cid & 15;
        int d = dsts[row];
        float a = av[row];
        bf16x8 tv = *(const bf16x8*)(T16 + (size_t)d*128 + ch*8);
        union { short s[8]; int4 v; } u;
        #pragma unroll
        for (int i=0; i<8; ++i) u.s[i] = f2bf(elu1(a * bf2f(tv[i])));
        *(int4*)(c_lds + row*272 + ch*16) = u.v;
    }
    __syncthreads();
    const int w = t >> 6, lane = t & 63;
    const int l15 = lane & 15, lhi = lane >> 4;
    const int jb = w*16 + l15;
    // ---- gi GEMM ----
    f32x4 gi[4][3];
    #pragma unroll
    for (int g=0; g<3; ++g){
        float bv = bih[g*128 + jb];
        #pragma unroll
        for (int m=0; m<4; ++m) gi[m][g] = (f32x4){bv, bv, bv, bv};
    }
    #pragma unroll
    for (int ks=0; ks<4; ++ks){
        bf16x8 cf[4];
        #pragma unroll
        for (int m=0; m<4; ++m)
            cf[m] = *(const bf16x8*)(c_lds + (m*16+l15)*272 + ks*64 + (lhi<<4));
        #pragma unroll
        for (int g=0; g<3; ++g){
            bf16x8 wf = *(const bf16x8*)(wihp + (size_t)(((g*8+w)*4 + ks)*64 + lane)*8);
            #pragma unroll
            for (int m=0; m<4; ++m)
                gi[m][g] = __builtin_amdgcn_mfma_f32_16x16x32_bf16(cf[m], wf, gi[m][g], 0, 0, 0);
        }
    }
    // ---- GRU epilogue (gh/hp gathered bf16, L1-hot due to sorting) ----
    float hreg[4][4];
    #pragma unroll
    for (int m=0; m<4; ++m){
        #pragma unroll
        for (int reg=0; reg<4; ++reg){
            int e = m*16 + lhi*4 + reg;
            int d = dsts[e];
            const short* gh = GH16 + (size_t)d*384;
            float r = sigm(gi[m][0][reg] + bf2f(gh[jb]));
            float z = sigm(gi[m][1][reg] + bf2f(gh[128+jb]));
            float n = tanh_fast(gi[m][2][reg] + r*bf2f(gh[256+jb]));
            float hp = bf2f(HP16[(size_t)d*128 + jb]);
            hreg[m][reg] = (1.f - z)*n + z*hp;
        }
    }
    __syncthreads();   // c reads done; smem becomes h[64][132] fp32
    {
        float* hlds = (float*)smem;
        #pragma unroll
        for (int m=0; m<4; ++m){
            #pragma unroll
            for (int reg=0; reg<4; ++reg){
                int e = m*16 + lhi*4 + reg;
                hlds[e*132 + jb] = hreg[m][reg];
            }
        }
    }
    __syncthreads();
    // ---- run-compressed scatter-add (sorted dst -> few atomics) ----
    {
        const int j = t & 127, eg = t >> 7;
        const float* hlds = (const float*)smem;
        float acc = 0.f; int prev = -1;
        #pragma unroll
        for (int el=0; el<16; ++el){
            int e = eg*16 + el;
            int d = dsts[e];
            float v = hlds[e*132 + j];
            if (d == prev) acc += v;
            else {
                if (prev >= 0) atomicAdd(out + (size_t)prev*128 + j, acc);
                acc = v; prev = d;
            }
        }
        atomicAdd(out + (size_t)prev*128 + j, acc);
    }
}

extern "C" void kernel_launch(void* const* d_in, const int* in_sizes, int n_in,
                              void* d_out, int out_size, void* d_ws, size_t ws_size,
                              hipStream_t stream) {
    const float* x    = (const float*)d_in[0];
    const int*   eidx = (const int*)d_in[1];
    const int*   esrc = eidx;
    const int*   edst = eidx + NE;
    const float* ea   = (const float*)d_in[2];
    const float* a_w  = (const float*)d_in[3];
    const float* a_b  = (const float*)d_in[4];
    const float* n_w  = (const float*)d_in[5];
    const float* n_b  = (const float*)d_in[6];
    const float* al_w0= (const float*)d_in[7];
    const float* al_b0= (const float*)d_in[8];
    const float* t_w0 = (const float*)d_in[9];
    const float* t_b0 = (const float*)d_in[10];
    const float* wih0 = (const float*)d_in[11];
    const float* whh0 = (const float*)d_in[12];
    const float* bih0 = (const float*)d_in[13];
    const float* bhh0 = (const float*)d_in[14];
    const float* al_w1= (const float*)d_in[15];
    const float* al_b1= (const float*)d_in[16];
    const float* t_w1 = (const float*)d_in[17];
    const float* t_b1 = (const float*)d_in[18];
    const float* wih1 = (const float*)d_in[19];
    const float* whh1 = (const float*)d_in[20];
    const float* bih1 = (const float*)d_in[21];
    const float* bhh1 = (const float*)d_in[22];

    float* ws   = (float*)d_ws;
    float* out0 = ws;                               // NN*128 f
    float* avu  = out0 + (size_t)NN*128;            // NE
    float* evu_tmp = avu + NE;                      // NE
    float* di   = evu_tmp + NE;                     // NN
    float* dj   = di + NN;                          // NN
    unsigned* hist_d = (unsigned*)(dj + NN);        // NN
    unsigned* hist_s = hist_d + NN;                 // NN (contiguous with hist_d for one memset)
    unsigned* cur_d  = hist_s + NN;                 // NN
    unsigned* cur_s  = cur_d + NN;                  // NN
    int* srcptr = (int*)(cur_s + NN);               // NN+1
    int* se_dst  = srcptr + NN + 1;                 // NE
    int* inv_dst = se_dst + NE;                     // NE
    int* se2_id  = inv_dst + NE;                    // NE
    int* se2_dst = se2_id + NE;                     // NE
    short* A16  = (short*)(se2_dst + NE);           // NN*128
    short* BX16 = A16 + (size_t)NN*128;             // B16 (l0) then x16 (l1)
    short* T16  = BX16 + (size_t)NN*128;            // NN*128
    short* GH16 = T16 + (size_t)NN*128;             // NN*384
    short* wp0  = GH16 + (size_t)NN*384;            // 49152 each
    short* wp1  = wp0 + 49152;
    short* wh0p = wp1 + 49152;
    short* wh1p = wh0p + 49152;
    short* tp0  = wh1p + 49152;                     // 16384 each
    short* tp1  = tp0 + 16384;

    hipMemsetAsync(out0, 0, (size_t)NN*128*sizeof(float), stream);
    hipMemsetAsync(d_out, 0, (size_t)NN*128*sizeof(float), stream);
    hipMemsetAsync(hist_d, 0, (size_t)2*NN*sizeof(unsigned), stream);

    dim3 blk(256);
    k_pack6<<<dim3(896), blk, 0, stream>>>(wih0, wih1, whh0, whh1, t_w0, t_w1,
                                           wp0, wp1, wh0p, wh1p, tp0, tp1);
    k_hist2<<<dim3((NE+255)/256), blk, 0, stream>>>(esrc, edst, hist_d, hist_s);
    k_scan2<<<dim3(2), dim3(1024), 0, stream>>>(hist_d, cur_d, hist_s, cur_s, srcptr);
    k_scatter2<<<dim3((NE+255)/256), blk, 0, stream>>>(esrc, edst, cur_d, cur_s,
                                                       se_dst, inv_dst, se2_id, se2_dst);
    // ---- layer 0 ----
    k_l0_node<<<dim3((NN+31)/32), blk, 0, stream>>>(x, a_w, a_b, n_w, n_b, al_w0,
                                                    A16, BX16, di);
    k_node_prep<<<dim3((NN+63)/64), dim3(512), 0, stream>>>(A16, tp0, t_b0, wh0p, bhh0, T16, GH16);
    k_align0<<<dim3((NN+3)/4), blk, 0, stream>>>(srcptr, se2_id, se2_dst, inv_dst,
                                                 ea, BX16, n_w, al_w0, al_b0, di, evu_tmp, avu);
    k_edge_gru<<<dim3(NE/64), dim3(512), 0, stream>>>(se_dst, avu, T16, GH16, A16,
                                                      wp0, bih0, out0);
    // ---- layer 1 ----
    k_l1_prep<<<dim3((NN+63)/64), dim3(512), 0, stream>>>(out0, al_w1, tp1, t_b1, wh1p, bhh1,
                                                          BX16, di, dj, T16, GH16);
    k_align1<<<dim3((NN+3)/4), blk, 0, stream>>>(srcptr, se2_id, se2_dst, inv_dst,
                                                 di, dj, al_b1, evu_tmp, avu);
    k_edge_gru<<<dim3(NE/64), dim3(512), 0, stream>>>(se_dst, avu, T16, GH16, BX16,
                                                      wp1, bih1, (float*)d_out);
}